// Round 10
// baseline (1611.512 us; speedup 1.0000x reference)
//
#include <hip/hip_runtime.h>
#include <cmath>

#define QLEN 300
#define BATCH 16
#define SLEN 1024
#define DM 256
#define DD 512
#define FFND 1024
#define NQROWS (QLEN*BATCH)   // 4800
#define NMROWS (SLEN*BATCH)   // 16384
#define LQPAD 304
#define SAKPAD 320
#define NSCA 4

typedef __attribute__((ext_vector_type(8))) short short8;
typedef __attribute__((ext_vector_type(4))) float f32x4;
typedef __attribute__((ext_vector_type(4))) unsigned short ushort4_;

__device__ __forceinline__ float sigmoidf_(float x){ return 1.f/(1.f+expf(-x)); }

__device__ __forceinline__ unsigned short f2bf(float x){
  unsigned u = __float_as_uint(x);
  unsigned r = (u + 0x7FFFu + ((u >> 16) & 1u)) >> 16;
  return (unsigned short)r;
}
__device__ __forceinline__ float bf2f(unsigned short u){
  return __uint_as_float(((unsigned)u) << 16);
}

// async global->LDS, 16B per lane; dest = wave-uniform base + lane*16
__device__ __forceinline__ void gload16(const void* g, void* l) {
  __builtin_amdgcn_global_load_lds((const __attribute__((address_space(1))) unsigned int*)g,
                                   (__attribute__((address_space(3))) unsigned int*)l, 16, 0, 0);
}

// ========== weight transpose + f32->bf16 (+scale) : W[K,N] -> Wt[N,K] ==========
__global__ __launch_bounds__(256) void transpose_cvt(
    const float* __restrict__ W, unsigned short* __restrict__ Wt, int K, int N,
    size_t zsrc, size_t zdst, float scale)
{
  __shared__ float T[32][33];
  int n0 = blockIdx.x*32, k0 = blockIdx.y*32;
  size_t zs = (size_t)blockIdx.z * zsrc;
  size_t zd = (size_t)blockIdx.z * zdst;
  int tx = threadIdx.x & 31, ty = threadIdx.x >> 5;
  #pragma unroll
  for (int j = 0; j < 32; j += 8)
    T[ty+j][tx] = W[zs + (size_t)(k0+ty+j)*N + n0+tx];
  __syncthreads();
  #pragma unroll
  for (int j = 0; j < 32; j += 8)
    Wt[zd + (size_t)(n0+ty+j)*K + k0+tx] = f2bf(T[tx][ty+j] * scale);
}

__global__ void concat_bias(const float* __restrict__ b1, const float* __restrict__ b2,
                            float* __restrict__ out)
{
  int i = blockIdx.x*256 + threadIdx.x;
  if (i < 256) out[i] = b1[i];
  else if (i < 512) out[i] = b2[i-256];
}

// ================= gemm2: pipelined bf16 MFMA GEMM, BN=128, BK=64 =================
// C = act(A @ Wt^T + bias). A bf16 [M,lda]; Wt bf16 [N,K].
// OUTMODE 0: f32 [M,N]; 1: bf16 [M,N];
// OUTMODE 2: bf16 head rows [(b*(N/64)+h)*Laux + q][64]  (rowg = q*16+b)
template<int BM, int OUTMODE, bool RELU>
__global__ __launch_bounds__(256) void gemm2(
    const unsigned short* __restrict__ Ab, const unsigned short* __restrict__ Wt,
    const float* __restrict__ bias, void* __restrict__ Cptr,
    int M, int N, int K, int lda, int Laux)
{
  __shared__ __align__(16) unsigned short As[2][BM*64];
  __shared__ __align__(16) unsigned short Bs[2][128*64];
  const int tid = threadIdx.x;
  const int w = tid >> 6, lane = tid & 63;
  const int bm = blockIdx.y*BM, bn = blockIdx.x*128;
  const int wm = w >> 1, wn = w & 1;
  const int c = lane & 15, hi = lane >> 4;
  constexpr int MR = (BM + 31)/32 < 1 ? 1 : BM/32;
  f32x4 acc[MR < 1 ? 1 : MR][4] = {};
  const int lrow8 = lane >> 3;
  const int lcol  = ((lane & 7) ^ lrow8) << 3;
  const int nt = K >> 6;

  auto stage = [&](int buf, int k0) {
    #pragma unroll
    for (int it = 0; it < BM/32; ++it) {
      int r = it*32 + w*8;
      gload16(&Ab[(size_t)(bm + r + lrow8)*lda + k0 + lcol], &As[buf][r*64]);
    }
    #pragma unroll
    for (int it = 0; it < 4; ++it) {
      int r = it*32 + w*8;
      gload16(&Wt[(size_t)(bn + r + lrow8)*K + k0 + lcol], &Bs[buf][r*64]);
    }
  };

  stage(0, 0);
  for (int t = 0; t < nt; ++t) {
    const int cur = t & 1;
    if (t + 1 < nt) {
      stage(cur ^ 1, (t+1) << 6);
      if constexpr (BM == 32)      asm volatile("s_waitcnt vmcnt(5)" ::: "memory");
      else if constexpr (BM == 64) asm volatile("s_waitcnt vmcnt(6)" ::: "memory");
      else                         asm volatile("s_waitcnt vmcnt(8)" ::: "memory");
    } else {
      asm volatile("s_waitcnt vmcnt(0)" ::: "memory");
    }
    __builtin_amdgcn_s_barrier();
    #pragma unroll
    for (int ks = 0; ks < 2; ++ks) {
      short8 a[MR], bf[4];
      #pragma unroll
      for (int mr = 0; mr < MR; ++mr) {
        int m = wm*(BM/2) + mr*16 + c;
        a[mr] = *reinterpret_cast<const short8*>(&As[cur][m*64 + ((ks*32 + hi*8) ^ ((m&7)<<3))]);
      }
      #pragma unroll
      for (int nr = 0; nr < 4; ++nr) {
        int n = wn*64 + nr*16 + c;
        bf[nr] = *reinterpret_cast<const short8*>(&Bs[cur][n*64 + ((ks*32 + hi*8) ^ ((n&7)<<3))]);
      }
      #pragma unroll
      for (int mr = 0; mr < MR; ++mr)
        #pragma unroll
        for (int nr = 0; nr < 4; ++nr)
          acc[mr][nr] = __builtin_amdgcn_mfma_f32_16x16x32_bf16(a[mr], bf[nr], acc[mr][nr], 0, 0, 0);
    }
    asm volatile("s_waitcnt lgkmcnt(0)" ::: "memory");
    __builtin_amdgcn_sched_barrier(0);
    __builtin_amdgcn_s_barrier();
  }
  const int hs = N >> 6;
  #pragma unroll
  for (int mr = 0; mr < MR; ++mr) {
    #pragma unroll
    for (int nr = 0; nr < 4; ++nr) {
      int colg = bn + wn*64 + nr*16 + c;
      float bv = bias ? bias[colg] : 0.f;
      #pragma unroll
      for (int r = 0; r < 4; ++r) {
        int rowg = bm + wm*(BM/2) + mr*16 + hi*4 + r;
        float v = acc[mr][nr][r] + bv;
        if (RELU) v = fmaxf(v, 0.f);
        if (OUTMODE == 0) {
          ((float*)Cptr)[(size_t)rowg*N + colg] = v;
        } else if (OUTMODE == 1) {
          ((unsigned short*)Cptr)[(size_t)rowg*N + colg] = f2bf(v);
        } else {
          int bb = rowg & 15, row = rowg >> 4, h = colg >> 6, dl = colg & 63;
          ((unsigned short*)Cptr)[(((size_t)bb*hs + h)*Laux + row)*64 + dl] = f2bf(v);
        }
      }
    }
  }
}

// ================= gemm2_vt: V-projection producing V^T, per-batch tiles ==========
template<int BM>
__global__ __launch_bounds__(256) void gemm2_vt(
    const unsigned short* __restrict__ Ab, const unsigned short* __restrict__ Wt,
    unsigned short* __restrict__ VT, int Lsrc, int K, int lda, int Lkpad, int tilesPerB)
{
  __shared__ __align__(16) unsigned short As[2][BM*64];
  __shared__ __align__(16) unsigned short Bs[2][128*64];
  const int tid = threadIdx.x;
  const int w = tid >> 6, lane = tid & 63;
  const int b = blockIdx.y / tilesPerB;
  const int qt = (blockIdx.y - b*tilesPerB) * BM;
  const int bn = blockIdx.x*128;
  const int wm = w >> 1, wn = w & 1;
  const int c = lane & 15, hi = lane >> 4;
  constexpr int MR = BM/32;
  f32x4 acc[MR][4] = {};
  const int lrow8 = lane >> 3;
  const int lcol  = ((lane & 7) ^ lrow8) << 3;
  const int nt = K >> 6;

  auto stage = [&](int buf, int k0) {
    #pragma unroll
    for (int it = 0; it < BM/32; ++it) {
      int r = it*32 + w*8;
      int q = qt + r + lrow8; if (q > Lsrc-1) q = Lsrc-1;
      gload16(&Ab[(size_t)(q*BATCH + b)*lda + k0 + lcol], &As[buf][r*64]);
    }
    #pragma unroll
    for (int it = 0; it < 4; ++it) {
      int r = it*32 + w*8;
      gload16(&Wt[(size_t)(bn + r + lrow8)*K + k0 + lcol], &Bs[buf][r*64]);
    }
  };

  stage(0, 0);
  for (int t = 0; t < nt; ++t) {
    const int cur = t & 1;
    if (t + 1 < nt) {
      stage(cur ^ 1, (t+1) << 6);
      if constexpr (BM == 64) asm volatile("s_waitcnt vmcnt(6)" ::: "memory");
      else                    asm volatile("s_waitcnt vmcnt(8)" ::: "memory");
    } else {
      asm volatile("s_waitcnt vmcnt(0)" ::: "memory");
    }
    __builtin_amdgcn_s_barrier();
    #pragma unroll
    for (int ks = 0; ks < 2; ++ks) {
      short8 a[MR], bf[4];
      #pragma unroll
      for (int mr = 0; mr < MR; ++mr) {
        int m = wm*(BM/2) + mr*16 + c;
        a[mr] = *reinterpret_cast<const short8*>(&As[cur][m*64 + ((ks*32 + hi*8) ^ ((m&7)<<3))]);
      }
      #pragma unroll
      for (int nr = 0; nr < 4; ++nr) {
        int n = wn*64 + nr*16 + c;
        bf[nr] = *reinterpret_cast<const short8*>(&Bs[cur][n*64 + ((ks*32 + hi*8) ^ ((n&7)<<3))]);
      }
      #pragma unroll
      for (int mr = 0; mr < MR; ++mr)
        #pragma unroll
        for (int nr = 0; nr < 4; ++nr)
          acc[mr][nr] = __builtin_amdgcn_mfma_f32_16x16x32_bf16(a[mr], bf[nr], acc[mr][nr], 0, 0, 0);
    }
    asm volatile("s_waitcnt lgkmcnt(0)" ::: "memory");
    __builtin_amdgcn_sched_barrier(0);
    __builtin_amdgcn_s_barrier();
  }
  #pragma unroll
  for (int mr = 0; mr < MR; ++mr) {
    #pragma unroll
    for (int nr = 0; nr < 4; ++nr) {
      int colg = bn + wn*64 + nr*16 + c;
      int h = colg >> 6, dl = colg & 63;
      int q0 = qt + wm*(BM/2) + mr*16 + hi*4;
      ushort4_ pack;
      #pragma unroll
      for (int r = 0; r < 4; ++r) pack[r] = f2bf(acc[mr][nr][r]);
      *reinterpret_cast<ushort4_*>(&VT[((size_t)(b*8 + h)*64 + dl)*Lkpad + q0]) = pack;
    }
  }
}

// ===== fused qs1+bbox1: A bf16 [M,lda]; N=512 (cols 0..255 -> bf16 C1, 256..511 -> f32 C2), ReLU =====
__global__ __launch_bounds__(256) void gemm_mfma_split(
    const unsigned short* __restrict__ Ab, const unsigned short* __restrict__ Wt,
    const float* __restrict__ bias, unsigned short* __restrict__ C1, float* __restrict__ C2,
    int M, int N, int K, int lda)
{
  __shared__ __align__(16) unsigned short As[64][72];
  __shared__ __align__(16) unsigned short Bs[64][72];
  const int tid = threadIdx.x;
  const int bm = blockIdx.y*64, bn = blockIdx.x*64;
  const int w = tid >> 6, lane = tid & 63;
  const int wm = w >> 1, wn = w & 1;
  const int c = lane & 15, hi = lane >> 4;
  const int sr = tid >> 3, sk = (tid & 7) * 8;
  f32x4 acc[2][2] = {};
  for (int k0 = 0; k0 < K; k0 += 64) {
    #pragma unroll
    for (int it = 0; it < 2; ++it) {
      int m = sr + it*32;
      short8 v = *reinterpret_cast<const short8*>(&Ab[(size_t)(bm+m)*lda + k0 + sk]);
      *reinterpret_cast<short8*>(&As[m][sk]) = v;
      short8 bv = *reinterpret_cast<const short8*>(&Wt[(size_t)(bn+m)*K + k0 + sk]);
      *reinterpret_cast<short8*>(&Bs[m][sk]) = bv;
    }
    __syncthreads();
    #pragma unroll
    for (int ks = 0; ks < 2; ++ks) {
      short8 a0 = *reinterpret_cast<const short8*>(&As[wm*32 + c][ks*32 + hi*8]);
      short8 a1 = *reinterpret_cast<const short8*>(&As[wm*32 + 16 + c][ks*32 + hi*8]);
      short8 b0 = *reinterpret_cast<const short8*>(&Bs[wn*32 + c][ks*32 + hi*8]);
      short8 b1 = *reinterpret_cast<const short8*>(&Bs[wn*32 + 16 + c][ks*32 + hi*8]);
      acc[0][0] = __builtin_amdgcn_mfma_f32_16x16x32_bf16(a0, b0, acc[0][0], 0, 0, 0);
      acc[0][1] = __builtin_amdgcn_mfma_f32_16x16x32_bf16(a0, b1, acc[0][1], 0, 0, 0);
      acc[1][0] = __builtin_amdgcn_mfma_f32_16x16x32_bf16(a1, b0, acc[1][0], 0, 0, 0);
      acc[1][1] = __builtin_amdgcn_mfma_f32_16x16x32_bf16(a1, b1, acc[1][1], 0, 0, 0);
    }
    __syncthreads();
  }
  #pragma unroll
  for (int mf = 0; mf < 2; ++mf) {
    #pragma unroll
    for (int nf = 0; nf < 2; ++nf) {
      int colg = bn + wn*32 + nf*16 + c;
      float bv = bias[colg];
      #pragma unroll
      for (int r = 0; r < 4; ++r) {
        int rowg = bm + wm*32 + mf*16 + hi*4 + r;
        float v = fmaxf(acc[mf][nf][r] + bv, 0.f);
        if (colg < 256) C1[(size_t)rowg*256 + colg] = f2bf(v);
        else            C2[(size_t)rowg*256 + (colg-256)] = v;
      }
    }
  }
}

// ================= attn2: pipelined MFMA flash attention (swapped QK^T) ==========
// Q rows at (b*qmul + h)*Lq (Wq pre-scaled by 0.125); K rows at (b*kmul + koff + h)*Lk;
// VT [(b*8+h)*64+d][Lkpad]. Defer-rescale THR=8. Pl stored swizzled (no padding):
// logical [q=c][key], 16B chunk index ^= (c&7) -> conflict-free write(8B)/read(16B),
// total LDS = 16384+16384+8192 = 40960 B -> 4 blocks/CU.
template<bool HAS_BIAS, bool MASK, int NS>
__global__ __launch_bounds__(256) void attn2(
    const unsigned short* __restrict__ Qh, const unsigned short* __restrict__ Kh,
    const unsigned short* __restrict__ VT, const float* __restrict__ bias,
    unsigned short* __restrict__ Ob, unsigned short* __restrict__ Opart, float* __restrict__ MLpart,
    int Lq, int Lk, int Lkpad, int qmul, int kmul, int koff)
{
  __shared__ __align__(16) unsigned short Ks[2][64*64];
  __shared__ __align__(16) unsigned short Vs[2][64*64];
  __shared__ __align__(16) unsigned short Pl[4][16*64];
  const int tid = threadIdx.x;
  const int w = tid >> 6, lane = tid & 63;
  const int c = lane & 15, hi = lane >> 4;
  const int bh = blockIdx.x;
  const int qt = blockIdx.y * 64;
  const int sp = blockIdx.z;
  const int b = bh >> 3, h = bh & 7;
  const int lrow8 = lane >> 3;
  const int lcol  = ((lane & 7) ^ lrow8) << 3;

  const int nt_tot = (Lk + 63) >> 6;
  const int t0 = (nt_tot * sp) / NS;
  const int t1 = (nt_tot * (sp + 1)) / NS;

  int qrow = qt + w*16 + c; if (qrow > Lq-1) qrow = Lq-1;
  const unsigned short* qptr = Qh + ((size_t)(b*qmul + h)*Lq + qrow)*64;
  short8 qf0 = *reinterpret_cast<const short8*>(qptr + hi*8);
  short8 qf1 = *reinterpret_cast<const short8*>(qptr + 32 + hi*8);
  const size_t kbase = (size_t)(b*kmul + koff + h)*Lk;

  float m_ = -1e30f, l_ = 0.f;
  f32x4 accO[4] = {};
  const int qbase = qt + w*16 + hi*4;

  auto stageKV = [&](int buf, int kt) {
    #pragma unroll
    for (int it = 0; it < 2; ++it) {
      int r = it*32 + w*8;
      int kr = kt + r + lrow8; if (MASK && kr > Lk-1) kr = Lk-1;
      gload16(&Kh[(kbase + kr)*64 + lcol], &Ks[buf][r*64]);
    }
    #pragma unroll
    for (int it = 0; it < 2; ++it) {
      int r = it*32 + w*8;
      gload16(&VT[((size_t)bh*64 + r + lrow8)*Lkpad + kt + lcol], &Vs[buf][r*64]);
    }
  };

  stageKV(0, t0 << 6);
  for (int t = t0; t < t1; ++t) {
    const int cur = (t - t0) & 1;
    const int kt = t << 6;
    float4 bs4[4];
    if (HAS_BIAS) {
      #pragma unroll
      for (int g = 0; g < 4; ++g)
        bs4[g] = *reinterpret_cast<const float4*>(
            &bias[((size_t)b*Lq + qrow)*Lk + kt + g*16 + hi*4]);
    }
    if (t + 1 < t1) {
      stageKV(cur ^ 1, (t+1) << 6);
      asm volatile("s_waitcnt vmcnt(4)" ::: "memory");
    } else {
      asm volatile("s_waitcnt vmcnt(0)" ::: "memory");
    }
    __builtin_amdgcn_s_barrier();
    // ---- S^T = K Q^T  (scale folded into Q projection) ----
    f32x4 s[4] = {};
    __builtin_amdgcn_s_setprio(1);
    #pragma unroll
    for (int g = 0; g < 4; ++g) {
      int m = g*16 + c;
      short8 kb0 = *reinterpret_cast<const short8*>(&Ks[cur][m*64 + ((hi*8)      ^ ((m&7)<<3))]);
      short8 kb1 = *reinterpret_cast<const short8*>(&Ks[cur][m*64 + ((32 + hi*8) ^ ((m&7)<<3))]);
      s[g] = __builtin_amdgcn_mfma_f32_16x16x32_bf16(kb0, qf0, s[g], 0, 0, 0);
      s[g] = __builtin_amdgcn_mfma_f32_16x16x32_bf16(kb1, qf1, s[g], 0, 0, 0);
    }
    __builtin_amdgcn_s_setprio(0);
    // ---- logits + lane-local online softmax ----
    float tmax = -1e30f;
    #pragma unroll
    for (int g = 0; g < 4; ++g) {
      #pragma unroll
      for (int r = 0; r < 4; ++r) {
        float v = s[g][r];
        if (HAS_BIAS) v += ((const float*)&bs4[g])[r];
        if (MASK && (kt + g*16 + hi*4 + r >= Lk)) v = -1e30f;
        s[g][r] = v;
        tmax = fmaxf(tmax, v);
      }
    }
    tmax = fmaxf(tmax, __shfl_xor(tmax, 16));
    tmax = fmaxf(tmax, __shfl_xor(tmax, 32));
    // T13 defer-rescale: skip when growth <= 8 (P bounded by e^8; ratio O/l exact)
    if (!__all(tmax - m_ <= 8.f)) {
      float newm = fmaxf(m_, tmax);
      float corr = __expf(m_ - newm);
      m_ = newm;
      l_ *= corr;
      float corr4[4];
      #pragma unroll
      for (int r = 0; r < 4; ++r) corr4[r] = __shfl(corr, hi*4 + r);
      #pragma unroll
      for (int dg = 0; dg < 4; ++dg)
        #pragma unroll
        for (int r = 0; r < 4; ++r) accO[dg][r] *= corr4[r];
    }
    float psum = 0.f;
    #pragma unroll
    for (int g = 0; g < 4; ++g) {
      ushort4_ pp;
      #pragma unroll
      for (int r = 0; r < 4; ++r) {
        float e = __expf(s[g][r] - m_);
        psum += e;
        pp[r] = f2bf(e);
      }
      // write P[q=c][keys g*16+hi*4..+3]: chunk (2g|(hi>>1)) ^ (c&7), half (hi&1)
      int idx = c*64 + ((((g<<1)|(hi>>1)) ^ (c&7))<<3) + ((hi&1)<<2);
      *reinterpret_cast<ushort4_*>(&Pl[w][idx]) = pp;
    }
    psum += __shfl_xor(psum, 16);
    psum += __shfl_xor(psum, 32);
    l_ += psum;
    // ---- O += P V ----
    __builtin_amdgcn_s_setprio(1);
    #pragma unroll
    for (int ks = 0; ks < 2; ++ks) {
      // read P[q=c][keys ks*32+hi*8..+7]: chunk (ks*4+hi) ^ (c&7)
      short8 pa = *reinterpret_cast<const short8*>(&Pl[w][c*64 + ((((ks<<2)|hi) ^ (c&7))<<3)]);
      #pragma unroll
      for (int dg = 0; dg < 4; ++dg) {
        int n = dg*16 + c;
        short8 vb = *reinterpret_cast<const short8*>(&Vs[cur][n*64 + ((ks*32 + hi*8) ^ ((n&7)<<3))]);
        accO[dg] = __builtin_amdgcn_mfma_f32_16x16x32_bf16(pa, vb, accO[dg], 0, 0, 0);
      }
    }
    __builtin_amdgcn_s_setprio(0);
    asm volatile("s_waitcnt lgkmcnt(0)" ::: "memory");
    __builtin_amdgcn_sched_barrier(0);
    __builtin_amdgcn_s_barrier();
  }
  // ---- epilogue ----
  if (NS == 1) {
    float l4[4];
    #pragma unroll
    for (int r = 0; r < 4; ++r) l4[r] = __shfl(l_, hi*4 + r);
    #pragma unroll
    for (int r = 0; r < 4; ++r) {
      int qg = qbase + r;
      if (qg < Lq) {
        float inv = 1.f / l4[r];
        #pragma unroll
        for (int dg = 0; dg < 4; ++dg)
          Ob[((size_t)qg*BATCH + b)*DD + h*64 + 16*dg + c] = f2bf(accO[dg][r] * inv);
      }
    }
  } else {
    int qc = qt + w*16 + c;
    if (hi == 0 && qc < Lq) {
      size_t rowml = ((size_t)sp*128 + bh)*LQPAD + qc;
      MLpart[rowml*2]     = m_;
      MLpart[rowml*2 + 1] = l_;
    }
    #pragma unroll
    for (int r = 0; r < 4; ++r) {
      int qg = qbase + r;
      if (qg < Lq) {
        size_t rowo = ((size_t)sp*128 + bh)*LQPAD + qg;
        #pragma unroll
        for (int dg = 0; dg < 4; ++dg)
          Opart[rowo*64 + dg*16 + c] = f2bf(accO[dg][r]);
      }
    }
  }
}

// combine NSR partials -> bf16 out [q*16+b][512]
template<int NSR>
__global__ __launch_bounds__(256) void attn_reduce(
    const unsigned short* __restrict__ Opart, const float* __restrict__ MLpart,
    unsigned short* __restrict__ Ob, int Lq)
{
  int w = threadIdx.x >> 6, lane = threadIdx.x & 63;
  int pair = blockIdx.x*4 + w;
  if (pair >= 128*Lq) return;
  int bh = pair / Lq, q = pair - bh*Lq;
  size_t rr[NSR];
  float m[NSR], l[NSR], M = -1e30f;
  #pragma unroll
  for (int s = 0; s < NSR; ++s) {
    rr[s] = ((size_t)s*128 + bh)*LQPAD + q;
    m[s] = MLpart[rr[s]*2];
    l[s] = MLpart[rr[s]*2 + 1];
    M = fmaxf(M, m[s]);
  }
  float o = 0.f, L = 0.f;
  #pragma unroll
  for (int s = 0; s < NSR; ++s) {
    float wg = __expf(m[s] - M);
    o += wg * bf2f(Opart[rr[s]*64 + lane]);
    L += wg * l[s];
  }
  int b = bh >> 3, h = bh & 7;
  Ob[((size_t)q*BATCH + b)*DD + h*64 + lane] = f2bf(o / L);
}

// ================= f32 GEMM (pre-loop rp MLP only) =================
__global__ __launch_bounds__(256) void gemm_f32(
    const float* __restrict__ A, const float* __restrict__ A2,
    const float* __restrict__ W, const float* __restrict__ bias,
    float* __restrict__ C, int M, int N, int K, int lda, int relu)
{
  __shared__ __align__(16) float As[16][68];
  __shared__ __align__(16) float Bs[16][68];
  const int tid = threadIdx.x;
  const int bm = blockIdx.y * 64, bn = blockIdx.x * 64;
  const int tx = tid & 15, ty = tid >> 4;
  const int ar = tid >> 4, ac = tid & 15;
  const int bk = tid >> 6, bnn = tid & 63;
  float acc[4][4] = {};
  for (int k0 = 0; k0 < K; k0 += 16) {
    #pragma unroll
    for (int i = 0; i < 4; ++i) {
      int row = ar + i*16;
      float v = A[(size_t)(bm+row)*lda + (k0+ac)];
      if (A2) v += A2[(size_t)(bm+row)*lda + (k0+ac)];
      As[ac][row] = v;
    }
    #pragma unroll
    for (int i = 0; i < 4; ++i) {
      int kk = bk + i*4;
      Bs[kk][bnn] = W[(size_t)(k0+kk)*N + (bn+bnn)];
    }
    __syncthreads();
    #pragma unroll
    for (int k = 0; k < 16; ++k) {
      float4 a4 = *reinterpret_cast<const float4*>(&As[k][ty*4]);
      float4 b4 = *reinterpret_cast<const float4*>(&Bs[k][tx*4]);
      float a[4] = {a4.x,a4.y,a4.z,a4.w};
      float bb[4] = {b4.x,b4.y,b4.z,b4.w};
      #pragma unroll
      for (int i=0;i<4;++i)
        #pragma unroll
        for (int j=0;j<4;++j)
          acc[i][j] = fmaf(a[i], bb[j], acc[i][j]);
    }
    __syncthreads();
  }
  float vb[4] = {0.f,0.f,0.f,0.f};
  if (bias) {
    float4 b4 = *reinterpret_cast<const float4*>(&bias[bn + tx*4]);
    vb[0]=b4.x; vb[1]=b4.y; vb[2]=b4.z; vb[3]=b4.w;
  }
  #pragma unroll
  for (int i=0;i<4;++i) {
    int row = bm + ty*4 + i;
    float r0 = acc[i][0]+vb[0], r1 = acc[i][1]+vb[1], r2 = acc[i][2]+vb[2], r3 = acc[i][3]+vb[3];
    if (relu){ r0=fmaxf(r0,0.f); r1=fmaxf(r1,0.f); r2=fmaxf(r2,0.f); r3=fmaxf(r3,0.f); }
    float4 o; o.x=r0; o.y=r1; o.z=r2; o.w=r3;
    *reinterpret_cast<float4*>(&C[(size_t)row*N + bn + tx*4]) = o;
  }
}

__global__ __launch_bounds__(256) void gemm_skinny(
    const float* __restrict__ A, const float* __restrict__ W, const float* __restrict__ bias,
    float* __restrict__ C, int M, int N, int K, int lda)
{
  int wid = threadIdx.x >> 6, lane = threadIdx.x & 63;
  int row = blockIdx.x * 4 + wid;
  if (row >= M) return;
  float acc[4] = {0.f,0.f,0.f,0.f};
  for (int k = lane; k < K; k += 64) {
    float av = A[(size_t)row*lda + k];
    for (int n = 0; n < N; ++n) acc[n] += av * W[(size_t)k*N + n];
  }
  for (int off = 32; off; off >>= 1)
    for (int n = 0; n < N; ++n) acc[n] += __shfl_down(acc[n], off);
  if (lane == 0)
    for (int n = 0; n < N; ++n) C[(size_t)row*N + n] = acc[n] + bias[n];
}

__global__ void sine_embed_kernel(const float* __restrict__ refb, float* __restrict__ sine)
{
  int idx = blockIdx.x*blockDim.x + threadIdx.x;
  if (idx >= NQROWS*DM) return;
  int r = idx >> 8, c = idx & 255;
  int j = c & 127;
  float coord = refb[r*2 + (c < 128 ? 1 : 0)];
  float s = sigmoidf_(coord);
  float freq = expf(-(float)(j >> 1) * (9.210340371976184f / 64.f));
  float v = s * 6.283185307179586f * freq;
  sine[idx] = (j & 1) ? cosf(v) : sinf(v);
}

__global__ void boxes_kernel(const float* __restrict__ t4, const float* __restrict__ refb,
                             float* __restrict__ boxes, float* __restrict__ cs)
{
  int idx = blockIdx.x*blockDim.x + threadIdx.x;
  if (idx >= NQROWS) return;
  int q = idx / BATCH, b = idx % BATCH;
  float cx = sigmoidf_(t4[idx*4+0] + refb[idx*2+0]);
  float cy = sigmoidf_(t4[idx*4+1] + refb[idx*2+1]);
  float w  = sigmoidf_(t4[idx*4+2]);
  float h  = sigmoidf_(t4[idx*4+3]);
  int o = b*QLEN + q;
  boxes[o*4+0] = cx - 0.5f*w;
  boxes[o*4+1] = cy - 0.5f*h;
  boxes[o*4+2] = cx + 0.5f*w;
  boxes[o*4+3] = cy + 0.5f*h;
  cs[o] = cx + cy;
}

__global__ void bias_kernel(const float* __restrict__ boxes, const float* __restrict__ cs,
                            float* __restrict__ bias)
{
  int idx = blockIdx.x*blockDim.x + threadIdx.x;
  const int QQ = QLEN*QLEN;
  if (idx >= BATCH*QQ) return;
  int b = idx / QQ, rem = idx - b*QQ;
  int i = rem / QLEN, j = rem - i*QLEN;
  float4 bi = *reinterpret_cast<const float4*>(&boxes[((size_t)b*QLEN + i)*4]);
  float4 bj = *reinterpret_cast<const float4*>(&boxes[((size_t)b*QLEN + j)*4]);
  float ai = (bi.z-bi.x)*(bi.w-bi.y);
  float aj = (bj.z-bj.x)*(bj.w-bj.y);
  float ltx = fmaxf(bi.x, bj.x), lty = fmaxf(bi.y, bj.y);
  float rbx = fminf(bi.z, bj.z), rby = fminf(bi.w, bj.w);
  float w = fmaxf(rbx-ltx, 0.f), h = fmaxf(rby-lty, 0.f);
  float inter = w*h;
  float iou = inter / (ai + aj - inter);
  bias[idx] = iou + ((cs[b*QLEN+i] > cs[b*QLEN+j]) ? 1.f : 0.f);
}

// memory / memory+pos -> bf16, once per call (loop-invariant)
__global__ void cvt_mem(const float* __restrict__ mem, const float* __restrict__ pos,
                        unsigned short* __restrict__ mb, unsigned short* __restrict__ mvb)
{
  int i = blockIdx.x*blockDim.x + threadIdx.x;
  if (i >= NMROWS*DD/8) return;
  size_t base = (size_t)i*8;
  float4 a0 = *reinterpret_cast<const float4*>(mem+base);
  float4 a1 = *reinterpret_cast<const float4*>(mem+base+4);
  float4 p0 = *reinterpret_cast<const float4*>(pos+base);
  float4 p1 = *reinterpret_cast<const float4*>(pos+base+4);
  short8 s1, s2;
  s1[0]=(short)f2bf(a0.x+p0.x); s1[1]=(short)f2bf(a0.y+p0.y); s1[2]=(short)f2bf(a0.z+p0.z); s1[3]=(short)f2bf(a0.w+p0.w);
  s1[4]=(short)f2bf(a1.x+p1.x); s1[5]=(short)f2bf(a1.y+p1.y); s1[6]=(short)f2bf(a1.z+p1.z); s1[7]=(short)f2bf(a1.w+p1.w);
  s2[0]=(short)f2bf(a0.x); s2[1]=(short)f2bf(a0.y); s2[2]=(short)f2bf(a0.z); s2[3]=(short)f2bf(a0.w);
  s2[4]=(short)f2bf(a1.x); s2[5]=(short)f2bf(a1.y); s2[6]=(short)f2bf(a1.z); s2[7]=(short)f2bf(a1.w);
  *reinterpret_cast<short8*>(mb+base)  = s1;
  *reinterpret_cast<short8*>(mvb+base) = s2;
}

// ===== residual + LN, in-place on X, emits bf16 Xb; EMIT 1: QIN=bf16(o+qp2); EMIT 2: QIN=bf16(o+qp2+sine*pt) =====
template<int EMIT>
__global__ __launch_bounds__(256) void ln_residual_t(
    float* __restrict__ X, const float* __restrict__ Y, unsigned short* __restrict__ Xb,
    const float* __restrict__ qp, const float* __restrict__ sine, const float* __restrict__ pt,
    unsigned short* __restrict__ QIN)
{
  int row = blockIdx.x, tid = threadIdx.x;
  size_t base = (size_t)row*DD;
  float v0 = X[base+tid]     + Y[base+tid];
  float v1 = X[base+tid+256] + Y[base+tid+256];
  float s = v0+v1, sq = v0*v0+v1*v1;
  for (int off = 32; off; off >>= 1) { s += __shfl_down(s,off); sq += __shfl_down(sq,off); }
  __shared__ float ss[4], ssq[4];
  int wid = tid>>6, lane = tid&63;
  if (lane==0){ ss[wid]=s; ssq[wid]=sq; }
  __syncthreads();
  if (tid==0){
    float a=ss[0]+ss[1]+ss[2]+ss[3], bsum=ssq[0]+ssq[1]+ssq[2]+ssq[3];
    float mean = a*(1.f/DD);
    float var  = bsum*(1.f/DD) - mean*mean;
    ss[0]=mean; ssq[0]=rsqrtf(fmaxf(var,0.f)+1e-5f);
  }
  __syncthreads();
  float mean = ss[0], inv = ssq[0];
  float o0 = (v0-mean)*inv, o1 = (v1-mean)*inv;
  X[base+tid]     = o0;  Xb[base+tid]     = f2bf(o0);
  X[base+tid+256] = o1;  Xb[base+tid+256] = f2bf(o1);
  if (EMIT >= 1) {
    size_t c2 = (size_t)row*256 + tid;
    float add = qp[c2];
    if (EMIT == 2) add += sine[c2]*pt[c2];
    QIN[base+tid]     = f2bf(o0 + add);
    QIN[base+tid+256] = f2bf(o1 + add);
  }
}

// init: X=tgt, Xb=bf16(tgt), QIN=bf16(tgt+qp2)
__global__ void init_x(const float* __restrict__ t, const float* __restrict__ qp,
                       float* __restrict__ X, unsigned short* __restrict__ Xb,
                       unsigned short* __restrict__ QIN, int n)
{
  int idx = blockIdx.x*blockDim.x + threadIdx.x;
  if (idx < n){
    float v = t[idx]; X[idx]=v; Xb[idx]=f2bf(v);
    int r = idx >> 9, c = idx & 511;
    QIN[idx] = f2bf(v + qp[(r<<8) + (c & 255)]);
  }
}

__global__ void copy_f32(const float* __restrict__ src, float* __restrict__ dst, int n)
{
  int idx = blockIdx.x*blockDim.x + threadIdx.x;
  if (idx < n) dst[idx] = src[idx];
}

extern "C" void kernel_launch(void* const* d_in, const int* in_sizes, int n_in,
                              void* d_out, int out_size, void* d_ws, size_t ws_size,
                              hipStream_t stream)
{
  const float* tgt       = (const float*)d_in[0];
  const float* memory    = (const float*)d_in[1];
  const float* pos       = (const float*)d_in[2];
  const float* query_pos = (const float*)d_in[3];
  const float* qs_W1 = (const float*)d_in[4];  const float* qs_b1 = (const float*)d_in[5];
  const float* qs_W2 = (const float*)d_in[6];  const float* qs_b2 = (const float*)d_in[7];
  const float* rp_W1 = (const float*)d_in[8];  const float* rp_b1 = (const float*)d_in[9];
  const float* rp_W2 = (const float*)d_in[10]; const float* rp_b2 = (const float*)d_in[11];
  const float* bb_W1 = (const float*)d_in[12]; const float* bb_b1 = (const float*)d_in[13];
  const float* bb_W2 = (const float*)d_in[14]; const float* bb_b2 = (const float*)d_in[15];
  const float* sa_Wq = (const float*)d_in[16]; const float* sa_Wk = (const float*)d_in[17];
  const float* sa_Wv = (const float*)d_in[18]; const float* sa_Wo = (const float*)d_in[19];
  const float* ca_Wq = (const float*)d_in[20]; const float* ca_Wk = (const float*)d_in[21];
  const float* ca_Wv = (const float*)d_in[22]; const float* ca_Wo = (const float*)d_in[23];
  const float* ff_W1 = (const float*)d_in[24]; const float* ff_b1 = (const float*)d_in[25];
  const float* ff_W2 = (const float*)d_in[26]; const float* ff_b2 = (const float*)d_in[27];

  // ---------- workspace layout ----------
  float* F = (float*)d_ws;
  size_t o = 0;
  float* X    = F + o; o += (size_t)NQROWS*DD;
  float* RES  = F + o; o += (size_t)NQROWS*DD;
  float* SINE = F + o; o += (size_t)NQROWS*DM;
  float* PT   = F + o; o += (size_t)NQROWS*DM;
  float* BIAS = F + o; o += (size_t)BATCH*QLEN*QLEN;
  float* REFB = F + o; o += (size_t)NQROWS*2;
  float* T4   = F + o; o += (size_t)NQROWS*4;
  float* BOX  = F + o; o += (size_t)NQROWS*4;
  float* CS   = F + o; o += (size_t)NQROWS;
  float* ML   = F + o; o += (size_t)NSCA*128*LQPAD*2;
  float* QBB  = F + o; o += 512;
  float* T256 = RES;   // alias (lifetime-disjoint)
  unsigned short* U = (unsigned short*)(F + o);
  size_t u = 0;
  unsigned short* Xb   = U + u; u += (size_t)NQROWS*DD;
  unsigned short* QIN  = U + u; u += (size_t)NQROWS*DD;
  unsigned short* PQb  = U + u; u += (size_t)NQROWS*DD;     // with PKb: fused SA QK buffer
  unsigned short* PKb  = U + u; u += (size_t)NMROWS*DD;
  unsigned short* PVb  = U + u; u += (size_t)NMROWS*DD;     // CA V^T [128*64][1024]
  unsigned short* VTsa = U + u; u += (size_t)128*64*SAKPAD; // SA V^T [128*64][320]
  unsigned short* OPARTU = U + u; u += (size_t)NSCA*128*LQPAD*64;
  unsigned short* T256b= U + u; u += (size_t)NQROWS*DM;
  unsigned short* MEMb = U + u; u += (size_t)NMROWS*DD;
  unsigned short* MEMVb= U + u; u += (size_t)NMROWS*DD;
  unsigned short* WtSqk= U + u; u += (size_t)6*2*DD*DD;     // fused [1024][512] per layer (Q half pre-scaled)
  unsigned short* WtSv = U + u; u += (size_t)6*DD*DD;
  unsigned short* WtSo = U + u; u += (size_t)6*DD*DD;
  unsigned short* WtCq = U + u; u += (size_t)6*DD*DD;       // pre-scaled by 0.125
  unsigned short* WtCk = U + u; u += (size_t)6*DD*DD;
  unsigned short* WtCv = U + u; u += (size_t)6*DD*DD;
  unsigned short* WtCo = U + u; u += (size_t)6*DD*DD;
  unsigned short* WtF1 = U + u; u += (size_t)6*DD*FFND;
  unsigned short* WtF2 = U + u; u += (size_t)6*DD*FFND;
  unsigned short* WtQB = U + u; u += (size_t)2*DM*DM;       // fused qs1|bbox1 [512][256]
  unsigned short* WtQ2 = U + u; u += (size_t)DM*DM;
  unsigned short* QKb  = PQb;   // fused SA QK output: 16 slots/batch x QLEN rows
  unsigned short* AOb  = QIN;
  unsigned short* HIDb = PKb;
  if (ws_size < o*sizeof(float) + u*sizeof(unsigned short)) return;

  dim3 B256(256);
  const int nTotal = NQROWS*DD;
  const size_t ZD = (size_t)DD*DD;
  const size_t ZM = (size_t)DM*DM;

  // ---------- weight transpose+cvt (Wq halves pre-scaled by 1/8, exact in bf16) ----------
  transpose_cvt<<<dim3(16,16,6), B256, 0, stream>>>(sa_Wq, WtSqk,      DD, DD, ZD, 2*ZD, 0.125f);
  transpose_cvt<<<dim3(16,16,6), B256, 0, stream>>>(sa_Wk, WtSqk + ZD, DD, DD, ZD, 2*ZD, 1.f);
  transpose_cvt<<<dim3(16,16,6), B256, 0, stream>>>(sa_Wv, WtSv, DD, DD, ZD, ZD, 1.f);
  transpose_cvt<<<dim3(16,16,6), B256, 0, stream>>>(sa_Wo, WtSo, DD, DD, ZD, ZD, 1.f);
  transpose_cvt<<<dim3(16,16,6), B256, 0, stream>>>(ca_Wq, WtCq, DD, DD, ZD, ZD, 0.125f);
  transpose_cvt<<<dim3(16,16,6), B256, 0, stream>>>(ca_Wk, WtCk, DD, DD, ZD, ZD, 1.f);
  transpose_cvt<<<dim3(16,16,6), B256, 0, stream>>>(ca_Wv, WtCv, DD, DD, ZD, ZD, 1.f);
  transpose_cvt<<<dim3(16,16,6), B256, 0, stream>>>(ca_Wo, WtCo, DD, DD, ZD, ZD, 1.f);
  transpose_cvt<<<dim3(32,16,6), B256, 0, stream>>>(ff_W1, WtF1, DD, FFND, (size_t)DD*FFND, (size_t)DD*FFND, 1.f);
  transpose_cvt<<<dim3(16,32,6), B256, 0, stream>>>(ff_W2, WtF2, FFND, DD, (size_t)DD*FFND, (size_t)DD*FFND, 1.f);
  transpose_cvt<<<dim3(8,8,1),  B256, 0, stream>>>(qs_W1, WtQB,      DM, DM, ZM, ZM, 1.f);
  transpose_cvt<<<dim3(8,8,1),  B256, 0, stream>>>(bb_W1, WtQB + ZM, DM, DM, ZM, ZM, 1.f);
  transpose_cvt<<<dim3(8,8,1),  B256, 0, stream>>>(qs_W2, WtQ2, DM, DM, ZM, ZM, 1.f);
  concat_bias<<<dim3(2), B256, 0, stream>>>(qs_b1, bb_b1, QBB);

  // ---------- pre-loop ----------
  init_x<<<dim3((nTotal+255)/256), B256, 0, stream>>>(tgt, query_pos, X, Xb, QIN, nTotal);
  cvt_mem<<<dim3(NMROWS*DD/8/256), B256, 0, stream>>>(memory, pos, MEMb, MEMVb);
  gemm_f32<<<dim3(DM/64, NQROWS/64), B256, 0, stream>>>(query_pos, nullptr, rp_W1, rp_b1, T256, NQROWS, DM, DM, DM, 1);
  gemm_skinny<<<dim3(NQROWS/4), B256, 0, stream>>>(T256, rp_W2, rp_b2, REFB, NQROWS, 2, DM, DM);
  sine_embed_kernel<<<dim3((NQROWS*DM+255)/256), B256, 0, stream>>>(REFB, SINE);

  const int nredu = (128*QLEN + 3) / 4;
  const int qtiles = (QLEN + 63) / 64;
  for (int l = 0; l < 6; ++l) {
    const size_t wo = (size_t)l*DD*DD, fo = (size_t)l*DD*FFND;
    const float* fb1 = ff_b1 + (size_t)l*FFND;
    const float* fb2 = ff_b2 + (size_t)l*DD;

    // fused qs1 (bf16 out) + bbox1 (f32 out), both ReLU, input Xb[:,256:]
    gemm_mfma_split<<<dim3(8, NQROWS/64), B256, 0, stream>>>(Xb+DM, WtQB, QBB, T256b, T256, NQROWS, 512, DM, DD);
    gemm2<32,0,false><<<dim3(DM/128, NQROWS/32), B256, 0, stream>>>(T256b, WtQ2, qs_b2, PT, NQROWS, DM, DM, DM, 0);
    gemm_skinny<<<dim3(NQROWS/4), B256, 0, stream>>>(T256, bb_W2, bb_b2, T4, NQROWS, 4, DM, DM);
    boxes_kernel<<<dim3((NQROWS+255)/256), B256, 0, stream>>>(T4, REFB, BOX, CS);
    bias_kernel<<<dim3((BATCH*QLEN*QLEN+255)/256), B256, 0, stream>>>(BOX, CS, BIAS);

    // ---- self-attention (QIN written by init_x / previous ln3) ----
    gemm2<64,2,false><<<dim3(1024/128, NQROWS/64), B256, 0, stream>>>(QIN, WtSqk + (size_t)l*2*ZD, nullptr, QKb, NQROWS, 1024, DD, DD, QLEN);
    gemm2_vt<64><<<dim3(DD/128, BATCH*5), B256, 0, stream>>>(Xb, WtSv+wo, VTsa, QLEN, DD, DD, SAKPAD, 5);
    attn2<true,true,2><<<dim3(128, qtiles, 2), B256, 0, stream>>>(QKb, QKb, VTsa, BIAS, nullptr, OPARTU, ML, QLEN, QLEN, SAKPAD, 16, 16, 8);
    attn_reduce<2><<<dim3(nredu), B256, 0, stream>>>(OPARTU, ML, AOb, QLEN);
    gemm2<32,0,false><<<dim3(DD/128, NQROWS/32), B256, 0, stream>>>(AOb, WtSo+wo, nullptr, RES, NQROWS, DD, DD, DD, 0);
    ln_residual_t<2><<<dim3(NQROWS), B256, 0, stream>>>(X, RES, Xb, query_pos, SINE, PT, QIN);

    // ---- cross-attention (QIN written by ln1 above) ----
    gemm2<32,2,false><<<dim3(DD/128, NQROWS/32), B256, 0, stream>>>(QIN, WtCq+wo, nullptr, PQb, NQROWS, DD, DD, DD, QLEN);
    gemm2<64,2,false><<<dim3(DD/128, NMROWS/64), B256, 0, stream>>>(MEMb,  WtCk+wo, nullptr, PKb, NMROWS, DD, DD, DD, SLEN);
    gemm2_vt<64><<<dim3(DD/128, BATCH*16), B256, 0, stream>>>(MEMVb, WtCv+wo, PVb, SLEN, DD, DD, SLEN, 16);
    attn2<false,false,NSCA><<<dim3(128, qtiles, NSCA), B256, 0, stream>>>(PQb, PKb, PVb, nullptr, nullptr, OPARTU, ML, QLEN, SLEN, SLEN, 8, 8, 0);
    attn_reduce<NSCA><<<dim3(nredu), B256, 0, stream>>>(OPARTU, ML, AOb, QLEN);
    gemm2<32,0,false><<<dim3(DD/128, NQROWS/32), B256, 0, stream>>>(AOb, WtCo+wo, nullptr, RES, NQROWS, DD, DD, DD, 0);
    ln_residual_t<0><<<dim3(NQROWS), B256, 0, stream>>>(X, RES, Xb, nullptr, nullptr, nullptr, nullptr);

    // ---- FFN ----
    gemm2<64,1,true ><<<dim3(FFND/128, NQROWS/64), B256, 0, stream>>>(Xb, WtF1+fo, fb1, HIDb, NQROWS, FFND, DD, DD, 0);
    gemm2<32,0,false><<<dim3(DD/128, NQROWS/32), B256, 0, stream>>>(HIDb, WtF2+fo, fb2, RES, NQROWS, DD, FFND, FFND, 0);
    ln_residual_t<1><<<dim3(NQROWS), B256, 0, stream>>>(X, RES, Xb, query_pos, nullptr, nullptr, QIN);
  }

  copy_f32<<<dim3((nTotal+255)/256), B256, 0, stream>>>(X, (float*)d_out, out_size);
}

// Round 11
// 1572.356 us; speedup vs baseline: 1.0249x; 1.0249x over previous
//
#include <hip/hip_runtime.h>
#include <cmath>

#define QLEN 300
#define BATCH 16
#define SLEN 1024
#define DM 256
#define DD 512
#define FFND 1024
#define NQROWS (QLEN*BATCH)   // 4800
#define NMROWS (SLEN*BATCH)   // 16384
#define LQPAD 304
#define SAKPAD 320

typedef __attribute__((ext_vector_type(8))) short short8;
typedef __attribute__((ext_vector_type(4))) float f32x4;
typedef __attribute__((ext_vector_type(4))) unsigned short ushort4_;

__device__ __forceinline__ float sigmoidf_(float x){ return 1.f/(1.f+expf(-x)); }

__device__ __forceinline__ unsigned short f2bf(float x){
  unsigned u = __float_as_uint(x);
  unsigned r = (u + 0x7FFFu + ((u >> 16) & 1u)) >> 16;
  return (unsigned short)r;
}
__device__ __forceinline__ float bf2f(unsigned short u){
  return __uint_as_float(((unsigned)u) << 16);
}

// async global->LDS, 16B per lane; dest = wave-uniform base + lane*16
__device__ __forceinline__ void gload16(const void* g, void* l) {
  __builtin_amdgcn_global_load_lds((const __attribute__((address_space(1))) unsigned int*)g,
                                   (__attribute__((address_space(3))) unsigned int*)l, 16, 0, 0);
}

// ========== weight transpose + f32->bf16 (+scale) : W[K,N] -> Wt[N,K] ==========
__global__ __launch_bounds__(256) void transpose_cvt(
    const float* __restrict__ W, unsigned short* __restrict__ Wt, int K, int N,
    size_t zsrc, size_t zdst, float scale)
{
  __shared__ float T[32][33];
  int n0 = blockIdx.x*32, k0 = blockIdx.y*32;
  size_t zs = (size_t)blockIdx.z * zsrc;
  size_t zd = (size_t)blockIdx.z * zdst;
  int tx = threadIdx.x & 31, ty = threadIdx.x >> 5;
  #pragma unroll
  for (int j = 0; j < 32; j += 8)
    T[ty+j][tx] = W[zs + (size_t)(k0+ty+j)*N + n0+tx];
  __syncthreads();
  #pragma unroll
  for (int j = 0; j < 32; j += 8)
    Wt[zd + (size_t)(n0+ty+j)*K + k0+tx] = f2bf(T[tx][ty+j] * scale);
}

__global__ void concat_bias(const float* __restrict__ b1, const float* __restrict__ b2,
                            float* __restrict__ out)
{
  int i = blockIdx.x*256 + threadIdx.x;
  if (i < 256) out[i] = b1[i];
  else if (i < 512) out[i] = b2[i-256];
}

// ================= gemm2: pipelined bf16 MFMA GEMM, BN=128, BK=64 =================
// C = act(A @ Wt^T + bias). A bf16 [M,lda]; Wt bf16 [N,K].
// OUTMODE 0: f32 [M,N]; 1: bf16 [M,N];
// OUTMODE 2: bf16 head rows [(b*(N/64)+h)*Laux + q][64]  (rowg = q*16+b)
template<int BM, int OUTMODE, bool RELU>
__global__ __launch_bounds__(256) void gemm2(
    const unsigned short* __restrict__ Ab, const unsigned short* __restrict__ Wt,
    const float* __restrict__ bias, void* __restrict__ Cptr,
    int M, int N, int K, int lda, int Laux)
{
  __shared__ __align__(16) unsigned short As[2][BM*64];
  __shared__ __align__(16) unsigned short Bs[2][128*64];
  const int tid = threadIdx.x;
  const int w = tid >> 6, lane = tid & 63;
  const int bm = blockIdx.y*BM, bn = blockIdx.x*128;
  const int wm = w >> 1, wn = w & 1;
  const int c = lane & 15, hi = lane >> 4;
  constexpr int MR = (BM + 31)/32 < 1 ? 1 : BM/32;
  f32x4 acc[MR < 1 ? 1 : MR][4] = {};
  const int lrow8 = lane >> 3;
  const int lcol  = ((lane & 7) ^ lrow8) << 3;
  const int nt = K >> 6;

  auto stage = [&](int buf, int k0) {
    #pragma unroll
    for (int it = 0; it < BM/32; ++it) {
      int r = it*32 + w*8;
      gload16(&Ab[(size_t)(bm + r + lrow8)*lda + k0 + lcol], &As[buf][r*64]);
    }
    #pragma unroll
    for (int it = 0; it < 4; ++it) {
      int r = it*32 + w*8;
      gload16(&Wt[(size_t)(bn + r + lrow8)*K + k0 + lcol], &Bs[buf][r*64]);
    }
  };

  stage(0, 0);
  for (int t = 0; t < nt; ++t) {
    const int cur = t & 1;
    if (t + 1 < nt) {
      stage(cur ^ 1, (t+1) << 6);
      if constexpr (BM == 32)      asm volatile("s_waitcnt vmcnt(5)" ::: "memory");
      else if constexpr (BM == 64) asm volatile("s_waitcnt vmcnt(6)" ::: "memory");
      else                         asm volatile("s_waitcnt vmcnt(8)" ::: "memory");
    } else {
      asm volatile("s_waitcnt vmcnt(0)" ::: "memory");
    }
    __builtin_amdgcn_s_barrier();
    #pragma unroll
    for (int ks = 0; ks < 2; ++ks) {
      short8 a[MR], bf[4];
      #pragma unroll
      for (int mr = 0; mr < MR; ++mr) {
        int m = wm*(BM/2) + mr*16 + c;
        a[mr] = *reinterpret_cast<const short8*>(&As[cur][m*64 + ((ks*32 + hi*8) ^ ((m&7)<<3))]);
      }
      #pragma unroll
      for (int nr = 0; nr < 4; ++nr) {
        int n = wn*64 + nr*16 + c;
        bf[nr] = *reinterpret_cast<const short8*>(&Bs[cur][n*64 + ((ks*32 + hi*8) ^ ((n&7)<<3))]);
      }
      #pragma unroll
      for (int mr = 0; mr < MR; ++mr)
        #pragma unroll
        for (int nr = 0; nr < 4; ++nr)
          acc[mr][nr] = __builtin_amdgcn_mfma_f32_16x16x32_bf16(a[mr], bf[nr], acc[mr][nr], 0, 0, 0);
    }
    asm volatile("s_waitcnt lgkmcnt(0)" ::: "memory");
    __builtin_amdgcn_sched_barrier(0);
    __builtin_amdgcn_s_barrier();
  }
  const int hs = N >> 6;
  #pragma unroll
  for (int mr = 0; mr < MR; ++mr) {
    #pragma unroll
    for (int nr = 0; nr < 4; ++nr) {
      int colg = bn + wn*64 + nr*16 + c;
      float bv = bias ? bias[colg] : 0.f;
      #pragma unroll
      for (int r = 0; r < 4; ++r) {
        int rowg = bm + wm*(BM/2) + mr*16 + hi*4 + r;
        float v = acc[mr][nr][r] + bv;
        if (RELU) v = fmaxf(v, 0.f);
        if (OUTMODE == 0) {
          ((float*)Cptr)[(size_t)rowg*N + colg] = v;
        } else if (OUTMODE == 1) {
          ((unsigned short*)Cptr)[(size_t)rowg*N + colg] = f2bf(v);
        } else {
          int bb = rowg & 15, row = rowg >> 4, h = colg >> 6, dl = colg & 63;
          ((unsigned short*)Cptr)[(((size_t)bb*hs + h)*Laux + row)*64 + dl] = f2bf(v);
        }
      }
    }
  }
}

// ================= gemm2_vt: V-projection producing V^T, per-batch tiles ==========
template<int BM>
__global__ __launch_bounds__(256) void gemm2_vt(
    const unsigned short* __restrict__ Ab, const unsigned short* __restrict__ Wt,
    unsigned short* __restrict__ VT, int Lsrc, int K, int lda, int Lkpad, int tilesPerB)
{
  __shared__ __align__(16) unsigned short As[2][BM*64];
  __shared__ __align__(16) unsigned short Bs[2][128*64];
  const int tid = threadIdx.x;
  const int w = tid >> 6, lane = tid & 63;
  const int b = blockIdx.y / tilesPerB;
  const int qt = (blockIdx.y - b*tilesPerB) * BM;
  const int bn = blockIdx.x*128;
  const int wm = w >> 1, wn = w & 1;
  const int c = lane & 15, hi = lane >> 4;
  constexpr int MR = BM/32;
  f32x4 acc[MR][4] = {};
  const int lrow8 = lane >> 3;
  const int lcol  = ((lane & 7) ^ lrow8) << 3;
  const int nt = K >> 6;

  auto stage = [&](int buf, int k0) {
    #pragma unroll
    for (int it = 0; it < BM/32; ++it) {
      int r = it*32 + w*8;
      int q = qt + r + lrow8; if (q > Lsrc-1) q = Lsrc-1;
      gload16(&Ab[(size_t)(q*BATCH + b)*lda + k0 + lcol], &As[buf][r*64]);
    }
    #pragma unroll
    for (int it = 0; it < 4; ++it) {
      int r = it*32 + w*8;
      gload16(&Wt[(size_t)(bn + r + lrow8)*K + k0 + lcol], &Bs[buf][r*64]);
    }
  };

  stage(0, 0);
  for (int t = 0; t < nt; ++t) {
    const int cur = t & 1;
    if (t + 1 < nt) {
      stage(cur ^ 1, (t+1) << 6);
      if constexpr (BM == 64) asm volatile("s_waitcnt vmcnt(6)" ::: "memory");
      else                    asm volatile("s_waitcnt vmcnt(8)" ::: "memory");
    } else {
      asm volatile("s_waitcnt vmcnt(0)" ::: "memory");
    }
    __builtin_amdgcn_s_barrier();
    #pragma unroll
    for (int ks = 0; ks < 2; ++ks) {
      short8 a[MR], bf[4];
      #pragma unroll
      for (int mr = 0; mr < MR; ++mr) {
        int m = wm*(BM/2) + mr*16 + c;
        a[mr] = *reinterpret_cast<const short8*>(&As[cur][m*64 + ((ks*32 + hi*8) ^ ((m&7)<<3))]);
      }
      #pragma unroll
      for (int nr = 0; nr < 4; ++nr) {
        int n = wn*64 + nr*16 + c;
        bf[nr] = *reinterpret_cast<const short8*>(&Bs[cur][n*64 + ((ks*32 + hi*8) ^ ((n&7)<<3))]);
      }
      #pragma unroll
      for (int mr = 0; mr < MR; ++mr)
        #pragma unroll
        for (int nr = 0; nr < 4; ++nr)
          acc[mr][nr] = __builtin_amdgcn_mfma_f32_16x16x32_bf16(a[mr], bf[nr], acc[mr][nr], 0, 0, 0);
    }
    asm volatile("s_waitcnt lgkmcnt(0)" ::: "memory");
    __builtin_amdgcn_sched_barrier(0);
    __builtin_amdgcn_s_barrier();
  }
  #pragma unroll
  for (int mr = 0; mr < MR; ++mr) {
    #pragma unroll
    for (int nr = 0; nr < 4; ++nr) {
      int colg = bn + wn*64 + nr*16 + c;
      int h = colg >> 6, dl = colg & 63;
      int q0 = qt + wm*(BM/2) + mr*16 + hi*4;
      ushort4_ pack;
      #pragma unroll
      for (int r = 0; r < 4; ++r) pack[r] = f2bf(acc[mr][nr][r]);
      *reinterpret_cast<ushort4_*>(&VT[((size_t)(b*8 + h)*64 + dl)*Lkpad + q0]) = pack;
    }
  }
}

// ===== fused qs1+bbox1: A bf16 [M,lda]; N=512 (cols 0..255 -> bf16 C1, 256..511 -> f32 C2), ReLU =====
__global__ __launch_bounds__(256) void gemm_mfma_split(
    const unsigned short* __restrict__ Ab, const unsigned short* __restrict__ Wt,
    const float* __restrict__ bias, unsigned short* __restrict__ C1, float* __restrict__ C2,
    int M, int N, int K, int lda)
{
  __shared__ __align__(16) unsigned short As[64][72];
  __shared__ __align__(16) unsigned short Bs[64][72];
  const int tid = threadIdx.x;
  const int bm = blockIdx.y*64, bn = blockIdx.x*64;
  const int w = tid >> 6, lane = tid & 63;
  const int wm = w >> 1, wn = w & 1;
  const int c = lane & 15, hi = lane >> 4;
  const int sr = tid >> 3, sk = (tid & 7) * 8;
  f32x4 acc[2][2] = {};
  for (int k0 = 0; k0 < K; k0 += 64) {
    #pragma unroll
    for (int it = 0; it < 2; ++it) {
      int m = sr + it*32;
      short8 v = *reinterpret_cast<const short8*>(&Ab[(size_t)(bm+m)*lda + k0 + sk]);
      *reinterpret_cast<short8*>(&As[m][sk]) = v;
      short8 bv = *reinterpret_cast<const short8*>(&Wt[(size_t)(bn+m)*K + k0 + sk]);
      *reinterpret_cast<short8*>(&Bs[m][sk]) = bv;
    }
    __syncthreads();
    #pragma unroll
    for (int ks = 0; ks < 2; ++ks) {
      short8 a0 = *reinterpret_cast<const short8*>(&As[wm*32 + c][ks*32 + hi*8]);
      short8 a1 = *reinterpret_cast<const short8*>(&As[wm*32 + 16 + c][ks*32 + hi*8]);
      short8 b0 = *reinterpret_cast<const short8*>(&Bs[wn*32 + c][ks*32 + hi*8]);
      short8 b1 = *reinterpret_cast<const short8*>(&Bs[wn*32 + 16 + c][ks*32 + hi*8]);
      acc[0][0] = __builtin_amdgcn_mfma_f32_16x16x32_bf16(a0, b0, acc[0][0], 0, 0, 0);
      acc[0][1] = __builtin_amdgcn_mfma_f32_16x16x32_bf16(a0, b1, acc[0][1], 0, 0, 0);
      acc[1][0] = __builtin_amdgcn_mfma_f32_16x16x32_bf16(a1, b0, acc[1][0], 0, 0, 0);
      acc[1][1] = __builtin_amdgcn_mfma_f32_16x16x32_bf16(a1, b1, acc[1][1], 0, 0, 0);
    }
    __syncthreads();
  }
  #pragma unroll
  for (int mf = 0; mf < 2; ++mf) {
    #pragma unroll
    for (int nf = 0; nf < 2; ++nf) {
      int colg = bn + wn*32 + nf*16 + c;
      float bv = bias[colg];
      #pragma unroll
      for (int r = 0; r < 4; ++r) {
        int rowg = bm + wm*32 + mf*16 + hi*4 + r;
        float v = fmaxf(acc[mf][nf][r] + bv, 0.f);
        if (colg < 256) C1[(size_t)rowg*256 + colg] = f2bf(v);
        else            C2[(size_t)rowg*256 + (colg-256)] = v;
      }
    }
  }
}

// ================= attn2: pipelined MFMA flash attention (swapped QK^T) ==========
// Q rows at (b*qmul + h)*Lq (Wq pre-scaled by 0.125); K rows at (b*kmul + koff + h)*Lk;
// VT [(b*8+h)*64+d][Lkpad]. Defer-rescale THR=8. Pl stored swizzled (no padding):
// logical [q=c][key], 16B chunk index ^= (c&7) -> conflict-free write(8B)/read(16B),
// total LDS = 16384+16384+8192 = 40960 B -> 4 blocks/CU.
template<bool HAS_BIAS, bool MASK, int NS>
__global__ __launch_bounds__(256) void attn2(
    const unsigned short* __restrict__ Qh, const unsigned short* __restrict__ Kh,
    const unsigned short* __restrict__ VT, const float* __restrict__ bias,
    unsigned short* __restrict__ Ob, unsigned short* __restrict__ Opart, float* __restrict__ MLpart,
    int Lq, int Lk, int Lkpad, int qmul, int kmul, int koff)
{
  __shared__ __align__(16) unsigned short Ks[2][64*64];
  __shared__ __align__(16) unsigned short Vs[2][64*64];
  __shared__ __align__(16) unsigned short Pl[4][16*64];
  const int tid = threadIdx.x;
  const int w = tid >> 6, lane = tid & 63;
  const int c = lane & 15, hi = lane >> 4;
  const int bh = blockIdx.x;
  const int qt = blockIdx.y * 64;
  const int sp = blockIdx.z;
  const int b = bh >> 3, h = bh & 7;
  const int lrow8 = lane >> 3;
  const int lcol  = ((lane & 7) ^ lrow8) << 3;

  const int nt_tot = (Lk + 63) >> 6;
  const int t0 = (nt_tot * sp) / NS;
  const int t1 = (nt_tot * (sp + 1)) / NS;

  int qrow = qt + w*16 + c; if (qrow > Lq-1) qrow = Lq-1;
  const unsigned short* qptr = Qh + ((size_t)(b*qmul + h)*Lq + qrow)*64;
  short8 qf0 = *reinterpret_cast<const short8*>(qptr + hi*8);
  short8 qf1 = *reinterpret_cast<const short8*>(qptr + 32 + hi*8);
  const size_t kbase = (size_t)(b*kmul + koff + h)*Lk;

  float m_ = -1e30f, l_ = 0.f;
  f32x4 accO[4] = {};
  const int qbase = qt + w*16 + hi*4;

  auto stageKV = [&](int buf, int kt) {
    #pragma unroll
    for (int it = 0; it < 2; ++it) {
      int r = it*32 + w*8;
      int kr = kt + r + lrow8; if (MASK && kr > Lk-1) kr = Lk-1;
      gload16(&Kh[(kbase + kr)*64 + lcol], &Ks[buf][r*64]);
    }
    #pragma unroll
    for (int it = 0; it < 2; ++it) {
      int r = it*32 + w*8;
      gload16(&VT[((size_t)bh*64 + r + lrow8)*Lkpad + kt + lcol], &Vs[buf][r*64]);
    }
  };

  stageKV(0, t0 << 6);
  for (int t = t0; t < t1; ++t) {
    const int cur = (t - t0) & 1;
    const int kt = t << 6;
    float4 bs4[4];
    if (HAS_BIAS) {
      #pragma unroll
      for (int g = 0; g < 4; ++g)
        bs4[g] = *reinterpret_cast<const float4*>(
            &bias[((size_t)b*Lq + qrow)*Lk + kt + g*16 + hi*4]);
    }
    if (t + 1 < t1) {
      stageKV(cur ^ 1, (t+1) << 6);
      asm volatile("s_waitcnt vmcnt(4)" ::: "memory");
    } else {
      asm volatile("s_waitcnt vmcnt(0)" ::: "memory");
    }
    __builtin_amdgcn_s_barrier();
    // ---- S^T = K Q^T  (scale folded into Q projection) ----
    f32x4 s[4] = {};
    __builtin_amdgcn_s_setprio(1);
    #pragma unroll
    for (int g = 0; g < 4; ++g) {
      int m = g*16 + c;
      short8 kb0 = *reinterpret_cast<const short8*>(&Ks[cur][m*64 + ((hi*8)      ^ ((m&7)<<3))]);
      short8 kb1 = *reinterpret_cast<const short8*>(&Ks[cur][m*64 + ((32 + hi*8) ^ ((m&7)<<3))]);
      s[g] = __builtin_amdgcn_mfma_f32_16x16x32_bf16(kb0, qf0, s[g], 0, 0, 0);
      s[g] = __builtin_amdgcn_mfma_f32_16x16x32_bf16(kb1, qf1, s[g], 0, 0, 0);
    }
    __builtin_amdgcn_s_setprio(0);
    // ---- logits + lane-local online softmax ----
    float tmax = -1e30f;
    #pragma unroll
    for (int g = 0; g < 4; ++g) {
      #pragma unroll
      for (int r = 0; r < 4; ++r) {
        float v = s[g][r];
        if (HAS_BIAS) v += ((const float*)&bs4[g])[r];
        if (MASK && (kt + g*16 + hi*4 + r >= Lk)) v = -1e30f;
        s[g][r] = v;
        tmax = fmaxf(tmax, v);
      }
    }
    tmax = fmaxf(tmax, __shfl_xor(tmax, 16));
    tmax = fmaxf(tmax, __shfl_xor(tmax, 32));
    // T13 defer-rescale: skip when growth <= 8 (P bounded by e^8; ratio O/l exact)
    if (!__all(tmax - m_ <= 8.f)) {
      float newm = fmaxf(m_, tmax);
      float corr = __expf(m_ - newm);
      m_ = newm;
      l_ *= corr;
      float corr4[4];
      #pragma unroll
      for (int r = 0; r < 4; ++r) corr4[r] = __shfl(corr, hi*4 + r);
      #pragma unroll
      for (int dg = 0; dg < 4; ++dg)
        #pragma unroll
        for (int r = 0; r < 4; ++r) accO[dg][r] *= corr4[r];
    }
    float psum = 0.f;
    #pragma unroll
    for (int g = 0; g < 4; ++g) {
      ushort4_ pp;
      #pragma unroll
      for (int r = 0; r < 4; ++r) {
        float e = __expf(s[g][r] - m_);
        psum += e;
        pp[r] = f2bf(e);
      }
      // write P[q=c][keys g*16+hi*4..+3]: chunk (2g|(hi>>1)) ^ (c&7), half (hi&1)
      int idx = c*64 + ((((g<<1)|(hi>>1)) ^ (c&7))<<3) + ((hi&1)<<2);
      *reinterpret_cast<ushort4_*>(&Pl[w][idx]) = pp;
    }
    psum += __shfl_xor(psum, 16);
    psum += __shfl_xor(psum, 32);
    l_ += psum;
    // ---- O += P V ----
    __builtin_amdgcn_s_setprio(1);
    #pragma unroll
    for (int ks = 0; ks < 2; ++ks) {
      // read P[q=c][keys ks*32+hi*8..+7]: chunk (ks*4+hi) ^ (c&7)
      short8 pa = *reinterpret_cast<const short8*>(&Pl[w][c*64 + ((((ks<<2)|hi) ^ (c&7))<<3)]);
      #pragma unroll
      for (int dg = 0; dg < 4; ++dg) {
        int n = dg*16 + c;
        short8 vb = *reinterpret_cast<const short8*>(&Vs[cur][n*64 + ((ks*32 + hi*8) ^ ((n&7)<<3))]);
        accO[dg] = __builtin_amdgcn_mfma_f32_16x16x32_bf16(pa, vb, accO[dg], 0, 0, 0);
      }
    }
    __builtin_amdgcn_s_setprio(0);
    asm volatile("s_waitcnt lgkmcnt(0)" ::: "memory");
    __builtin_amdgcn_sched_barrier(0);
    __builtin_amdgcn_s_barrier();
  }
  // ---- epilogue ----
  if (NS == 1) {
    float l4[4];
    #pragma unroll
    for (int r = 0; r < 4; ++r) l4[r] = __shfl(l_, hi*4 + r);
    #pragma unroll
    for (int r = 0; r < 4; ++r) {
      int qg = qbase + r;
      if (qg < Lq) {
        float inv = 1.f / l4[r];
        #pragma unroll
        for (int dg = 0; dg < 4; ++dg)
          Ob[((size_t)qg*BATCH + b)*DD + h*64 + 16*dg + c] = f2bf(accO[dg][r] * inv);
      }
    }
  } else {
    int qc = qt + w*16 + c;
    if (hi == 0 && qc < Lq) {
      size_t rowml = ((size_t)sp*128 + bh)*LQPAD + qc;
      MLpart[rowml*2]     = m_;
      MLpart[rowml*2 + 1] = l_;
    }
    #pragma unroll
    for (int r = 0; r < 4; ++r) {
      int qg = qbase + r;
      if (qg < Lq) {
        size_t rowo = ((size_t)sp*128 + bh)*LQPAD + qg;
        #pragma unroll
        for (int dg = 0; dg < 4; ++dg)
          Opart[rowo*64 + dg*16 + c] = f2bf(accO[dg][r]);
      }
    }
  }
}

// combine NSR partials -> bf16 out [q*16+b][512]
template<int NSR>
__global__ __launch_bounds__(256) void attn_reduce(
    const unsigned short* __restrict__ Opart, const float* __restrict__ MLpart,
    unsigned short* __restrict__ Ob, int Lq)
{
  int w = threadIdx.x >> 6, lane = threadIdx.x & 63;
  int pair = blockIdx.x*4 + w;
  if (pair >= 128*Lq) return;
  int bh = pair / Lq, q = pair - bh*Lq;
  size_t rr[NSR];
  float m[NSR], l[NSR], M = -1e30f;
  #pragma unroll
  for (int s = 0; s < NSR; ++s) {
    rr[s] = ((size_t)s*128 + bh)*LQPAD + q;
    m[s] = MLpart[rr[s]*2];
    l[s] = MLpart[rr[s]*2 + 1];
    M = fmaxf(M, m[s]);
  }
  float o = 0.f, L = 0.f;
  #pragma unroll
  for (int s = 0; s < NSR; ++s) {
    float wg = __expf(m[s] - M);
    o += wg * bf2f(Opart[rr[s]*64 + lane]);
    L += wg * l[s];
  }
  int b = bh >> 3, h = bh & 7;
  Ob[((size_t)q*BATCH + b)*DD + h*64 + lane] = f2bf(o / L);
}

// ================= f32 GEMM (pre-loop rp MLP only) =================
__global__ __launch_bounds__(256) void gemm_f32(
    const float* __restrict__ A, const float* __restrict__ A2,
    const float* __restrict__ W, const float* __restrict__ bias,
    float* __restrict__ C, int M, int N, int K, int lda, int relu)
{
  __shared__ __align__(16) float As[16][68];
  __shared__ __align__(16) float Bs[16][68];
  const int tid = threadIdx.x;
  const int bm = blockIdx.y * 64, bn = blockIdx.x * 64;
  const int tx = tid & 15, ty = tid >> 4;
  const int ar = tid >> 4, ac = tid & 15;
  const int bk = tid >> 6, bnn = tid & 63;
  float acc[4][4] = {};
  for (int k0 = 0; k0 < K; k0 += 16) {
    #pragma unroll
    for (int i = 0; i < 4; ++i) {
      int row = ar + i*16;
      float v = A[(size_t)(bm+row)*lda + (k0+ac)];
      if (A2) v += A2[(size_t)(bm+row)*lda + (k0+ac)];
      As[ac][row] = v;
    }
    #pragma unroll
    for (int i = 0; i < 4; ++i) {
      int kk = bk + i*4;
      Bs[kk][bnn] = W[(size_t)(k0+kk)*N + (bn+bnn)];
    }
    __syncthreads();
    #pragma unroll
    for (int k = 0; k < 16; ++k) {
      float4 a4 = *reinterpret_cast<const float4*>(&As[k][ty*4]);
      float4 b4 = *reinterpret_cast<const float4*>(&Bs[k][tx*4]);
      float a[4] = {a4.x,a4.y,a4.z,a4.w};
      float bb[4] = {b4.x,b4.y,b4.z,b4.w};
      #pragma unroll
      for (int i=0;i<4;++i)
        #pragma unroll
        for (int j=0;j<4;++j)
          acc[i][j] = fmaf(a[i], bb[j], acc[i][j]);
    }
    __syncthreads();
  }
  float vb[4] = {0.f,0.f,0.f,0.f};
  if (bias) {
    float4 b4 = *reinterpret_cast<const float4*>(&bias[bn + tx*4]);
    vb[0]=b4.x; vb[1]=b4.y; vb[2]=b4.z; vb[3]=b4.w;
  }
  #pragma unroll
  for (int i=0;i<4;++i) {
    int row = bm + ty*4 + i;
    float r0 = acc[i][0]+vb[0], r1 = acc[i][1]+vb[1], r2 = acc[i][2]+vb[2], r3 = acc[i][3]+vb[3];
    if (relu){ r0=fmaxf(r0,0.f); r1=fmaxf(r1,0.f); r2=fmaxf(r2,0.f); r3=fmaxf(r3,0.f); }
    float4 o; o.x=r0; o.y=r1; o.z=r2; o.w=r3;
    *reinterpret_cast<float4*>(&C[(size_t)row*N + bn + tx*4]) = o;
  }
}

__global__ __launch_bounds__(256) void gemm_skinny(
    const float* __restrict__ A, const float* __restrict__ W, const float* __restrict__ bias,
    float* __restrict__ C, int M, int N, int K, int lda)
{
  int wid = threadIdx.x >> 6, lane = threadIdx.x & 63;
  int row = blockIdx.x * 4 + wid;
  if (row >= M) return;
  float acc[4] = {0.f,0.f,0.f,0.f};
  for (int k = lane; k < K; k += 64) {
    float av = A[(size_t)row*lda + k];
    for (int n = 0; n < N; ++n) acc[n] += av * W[(size_t)k*N + n];
  }
  for (int off = 32; off; off >>= 1)
    for (int n = 0; n < N; ++n) acc[n] += __shfl_down(acc[n], off);
  if (lane == 0)
    for (int n = 0; n < N; ++n) C[(size_t)row*N + n] = acc[n] + bias[n];
}

__global__ void sine_embed_kernel(const float* __restrict__ refb, float* __restrict__ sine)
{
  int idx = blockIdx.x*blockDim.x + threadIdx.x;
  if (idx >= NQROWS*DM) return;
  int r = idx >> 8, c = idx & 255;
  int j = c & 127;
  float coord = refb[r*2 + (c < 128 ? 1 : 0)];
  float s = sigmoidf_(coord);
  float freq = expf(-(float)(j >> 1) * (9.210340371976184f / 64.f));
  float v = s * 6.283185307179586f * freq;
  sine[idx] = (j & 1) ? cosf(v) : sinf(v);
}

__global__ void boxes_kernel(const float* __restrict__ t4, const float* __restrict__ refb,
                             float* __restrict__ boxes, float* __restrict__ cs)
{
  int idx = blockIdx.x*blockDim.x + threadIdx.x;
  if (idx >= NQROWS) return;
  int q = idx / BATCH, b = idx % BATCH;
  float cx = sigmoidf_(t4[idx*4+0] + refb[idx*2+0]);
  float cy = sigmoidf_(t4[idx*4+1] + refb[idx*2+1]);
  float w  = sigmoidf_(t4[idx*4+2]);
  float h  = sigmoidf_(t4[idx*4+3]);
  int o = b*QLEN + q;
  boxes[o*4+0] = cx - 0.5f*w;
  boxes[o*4+1] = cy - 0.5f*h;
  boxes[o*4+2] = cx + 0.5f*w;
  boxes[o*4+3] = cy + 0.5f*h;
  cs[o] = cx + cy;
}

__global__ void bias_kernel(const float* __restrict__ boxes, const float* __restrict__ cs,
                            float* __restrict__ bias)
{
  int idx = blockIdx.x*blockDim.x + threadIdx.x;
  const int QQ = QLEN*QLEN;
  if (idx >= BATCH*QQ) return;
  int b = idx / QQ, rem = idx - b*QQ;
  int i = rem / QLEN, j = rem - i*QLEN;
  float4 bi = *reinterpret_cast<const float4*>(&boxes[((size_t)b*QLEN + i)*4]);
  float4 bj = *reinterpret_cast<const float4*>(&boxes[((size_t)b*QLEN + j)*4]);
  float ai = (bi.z-bi.x)*(bi.w-bi.y);
  float aj = (bj.z-bj.x)*(bj.w-bj.y);
  float ltx = fmaxf(bi.x, bj.x), lty = fmaxf(bi.y, bj.y);
  float rbx = fminf(bi.z, bj.z), rby = fminf(bi.w, bj.w);
  float w = fmaxf(rbx-ltx, 0.f), h = fmaxf(rby-lty, 0.f);
  float inter = w*h;
  float iou = inter / (ai + aj - inter);
  bias[idx] = iou + ((cs[b*QLEN+i] > cs[b*QLEN+j]) ? 1.f : 0.f);
}

// memory / memory+pos -> bf16, once per call (loop-invariant)
__global__ void cvt_mem(const float* __restrict__ mem, const float* __restrict__ pos,
                        unsigned short* __restrict__ mb, unsigned short* __restrict__ mvb)
{
  int i = blockIdx.x*blockDim.x + threadIdx.x;
  if (i >= NMROWS*DD/8) return;
  size_t base = (size_t)i*8;
  float4 a0 = *reinterpret_cast<const float4*>(mem+base);
  float4 a1 = *reinterpret_cast<const float4*>(mem+base+4);
  float4 p0 = *reinterpret_cast<const float4*>(pos+base);
  float4 p1 = *reinterpret_cast<const float4*>(pos+base+4);
  short8 s1, s2;
  s1[0]=(short)f2bf(a0.x+p0.x); s1[1]=(short)f2bf(a0.y+p0.y); s1[2]=(short)f2bf(a0.z+p0.z); s1[3]=(short)f2bf(a0.w+p0.w);
  s1[4]=(short)f2bf(a1.x+p1.x); s1[5]=(short)f2bf(a1.y+p1.y); s1[6]=(short)f2bf(a1.z+p1.z); s1[7]=(short)f2bf(a1.w+p1.w);
  s2[0]=(short)f2bf(a0.x); s2[1]=(short)f2bf(a0.y); s2[2]=(short)f2bf(a0.z); s2[3]=(short)f2bf(a0.w);
  s2[4]=(short)f2bf(a1.x); s2[5]=(short)f2bf(a1.y); s2[6]=(short)f2bf(a1.z); s2[7]=(short)f2bf(a1.w);
  *reinterpret_cast<short8*>(mb+base)  = s1;
  *reinterpret_cast<short8*>(mvb+base) = s2;
}

// ===== residual + LN, in-place on X, emits bf16 Xb; EMIT 1: QIN=bf16(o+qp2); EMIT 2: QIN=bf16(o+qp2+sine*pt) =====
template<int EMIT>
__global__ __launch_bounds__(256) void ln_residual_t(
    float* __restrict__ X, const float* __restrict__ Y, unsigned short* __restrict__ Xb,
    const float* __restrict__ qp, const float* __restrict__ sine, const float* __restrict__ pt,
    unsigned short* __restrict__ QIN)
{
  int row = blockIdx.x, tid = threadIdx.x;
  size_t base = (size_t)row*DD;
  float v0 = X[base+tid]     + Y[base+tid];
  float v1 = X[base+tid+256] + Y[base+tid+256];
  float s = v0+v1, sq = v0*v0+v1*v1;
  for (int off = 32; off; off >>= 1) { s += __shfl_down(s,off); sq += __shfl_down(sq,off); }
  __shared__ float ss[4], ssq[4];
  int wid = tid>>6, lane = tid&63;
  if (lane==0){ ss[wid]=s; ssq[wid]=sq; }
  __syncthreads();
  if (tid==0){
    float a=ss[0]+ss[1]+ss[2]+ss[3], bsum=ssq[0]+ssq[1]+ssq[2]+ssq[3];
    float mean = a*(1.f/DD);
    float var  = bsum*(1.f/DD) - mean*mean;
    ss[0]=mean; ssq[0]=rsqrtf(fmaxf(var,0.f)+1e-5f);
  }
  __syncthreads();
  float mean = ss[0], inv = ssq[0];
  float o0 = (v0-mean)*inv, o1 = (v1-mean)*inv;
  X[base+tid]     = o0;  Xb[base+tid]     = f2bf(o0);
  X[base+tid+256] = o1;  Xb[base+tid+256] = f2bf(o1);
  if (EMIT >= 1) {
    size_t c2 = (size_t)row*256 + tid;
    float add = qp[c2];
    if (EMIT == 2) add += sine[c2]*pt[c2];
    QIN[base+tid]     = f2bf(o0 + add);
    QIN[base+tid+256] = f2bf(o1 + add);
  }
}

// init: X=tgt, Xb=bf16(tgt), QIN=bf16(tgt+qp2)
__global__ void init_x(const float* __restrict__ t, const float* __restrict__ qp,
                       float* __restrict__ X, unsigned short* __restrict__ Xb,
                       unsigned short* __restrict__ QIN, int n)
{
  int idx = blockIdx.x*blockDim.x + threadIdx.x;
  if (idx < n){
    float v = t[idx]; X[idx]=v; Xb[idx]=f2bf(v);
    int r = idx >> 9, c = idx & 511;
    QIN[idx] = f2bf(v + qp[(r<<8) + (c & 255)]);
  }
}

__global__ void copy_f32(const float* __restrict__ src, float* __restrict__ dst, int n)
{
  int idx = blockIdx.x*blockDim.x + threadIdx.x;
  if (idx < n) dst[idx] = src[idx];
}

extern "C" void kernel_launch(void* const* d_in, const int* in_sizes, int n_in,
                              void* d_out, int out_size, void* d_ws, size_t ws_size,
                              hipStream_t stream)
{
  const float* tgt       = (const float*)d_in[0];
  const float* memory    = (const float*)d_in[1];
  const float* pos       = (const float*)d_in[2];
  const float* query_pos = (const float*)d_in[3];
  const float* qs_W1 = (const float*)d_in[4];  const float* qs_b1 = (const float*)d_in[5];
  const float* qs_W2 = (const float*)d_in[6];  const float* qs_b2 = (const float*)d_in[7];
  const float* rp_W1 = (const float*)d_in[8];  const float* rp_b1 = (const float*)d_in[9];
  const float* rp_W2 = (const float*)d_in[10]; const float* rp_b2 = (const float*)d_in[11];
  const float* bb_W1 = (const float*)d_in[12]; const float* bb_b1 = (const float*)d_in[13];
  const float* bb_W2 = (const float*)d_in[14]; const float* bb_b2 = (const float*)d_in[15];
  const float* sa_Wq = (const float*)d_in[16]; const float* sa_Wk = (const float*)d_in[17];
  const float* sa_Wv = (const float*)d_in[18]; const float* sa_Wo = (const float*)d_in[19];
  const float* ca_Wq = (const float*)d_in[20]; const float* ca_Wk = (const float*)d_in[21];
  const float* ca_Wv = (const float*)d_in[22]; const float* ca_Wo = (const float*)d_in[23];
  const float* ff_W1 = (const float*)d_in[24]; const float* ff_b1 = (const float*)d_in[25];
  const float* ff_W2 = (const float*)d_in[26]; const float* ff_b2 = (const float*)d_in[27];

  // ---------- workspace layout ----------
  float* F = (float*)d_ws;
  size_t o = 0;
  float* X    = F + o; o += (size_t)NQROWS*DD;
  float* RES  = F + o; o += (size_t)NQROWS*DD;
  float* SINE = F + o; o += (size_t)NQROWS*DM;
  float* PT   = F + o; o += (size_t)NQROWS*DM;
  float* BIAS = F + o; o += (size_t)BATCH*QLEN*QLEN;
  float* REFB = F + o; o += (size_t)NQROWS*2;
  float* T4   = F + o; o += (size_t)NQROWS*4;
  float* BOX  = F + o; o += (size_t)NQROWS*4;
  float* CS   = F + o; o += (size_t)NQROWS;
  float* ML   = F + o; o += (size_t)2*128*LQPAD*2;
  float* QBB  = F + o; o += 512;
  float* T256 = RES;   // alias (lifetime-disjoint)
  unsigned short* U = (unsigned short*)(F + o);
  size_t u = 0;
  unsigned short* Xb   = U + u; u += (size_t)NQROWS*DD;
  unsigned short* QIN  = U + u; u += (size_t)NQROWS*DD;
  unsigned short* PQb  = U + u; u += (size_t)NQROWS*DD;     // with PKb: fused SA QK buffer
  unsigned short* PKb  = U + u; u += (size_t)NMROWS*DD;
  unsigned short* PVb  = U + u; u += (size_t)NMROWS*DD;     // CA V^T [128*64][1024]
  unsigned short* VTsa = U + u; u += (size_t)128*64*SAKPAD; // SA V^T [128*64][320]
  unsigned short* OPARTU = U + u; u += (size_t)2*128*LQPAD*64;
  unsigned short* T256b= U + u; u += (size_t)NQROWS*DM;
  unsigned short* MEMb = U + u; u += (size_t)NMROWS*DD;
  unsigned short* MEMVb= U + u; u += (size_t)NMROWS*DD;
  unsigned short* WtSqk= U + u; u += (size_t)6*2*DD*DD;     // fused [1024][512] per layer (Q half pre-scaled)
  unsigned short* WtSv = U + u; u += (size_t)6*DD*DD;
  unsigned short* WtSo = U + u; u += (size_t)6*DD*DD;
  unsigned short* WtCq = U + u; u += (size_t)6*DD*DD;       // pre-scaled by 0.125
  unsigned short* WtCk = U + u; u += (size_t)6*DD*DD;
  unsigned short* WtCv = U + u; u += (size_t)6*DD*DD;
  unsigned short* WtCo = U + u; u += (size_t)6*DD*DD;
  unsigned short* WtF1 = U + u; u += (size_t)6*DD*FFND;
  unsigned short* WtF2 = U + u; u += (size_t)6*DD*FFND;
  unsigned short* WtQB = U + u; u += (size_t)2*DM*DM;       // fused qs1|bbox1 [512][256]
  unsigned short* WtQ2 = U + u; u += (size_t)DM*DM;
  unsigned short* QKb  = PQb;   // fused SA QK output: 16 slots/batch x QLEN rows
  unsigned short* AOb  = QIN;
  unsigned short* HIDb = PKb;
  if (ws_size < o*sizeof(float) + u*sizeof(unsigned short)) return;

  dim3 B256(256);
  const int nTotal = NQROWS*DD;
  const size_t ZD = (size_t)DD*DD;
  const size_t ZM = (size_t)DM*DM;

  // ---------- weight transpose+cvt (Wq halves pre-scaled by 1/8, exact in bf16) ----------
  transpose_cvt<<<dim3(16,16,6), B256, 0, stream>>>(sa_Wq, WtSqk,      DD, DD, ZD, 2*ZD, 0.125f);
  transpose_cvt<<<dim3(16,16,6), B256, 0, stream>>>(sa_Wk, WtSqk + ZD, DD, DD, ZD, 2*ZD, 1.f);
  transpose_cvt<<<dim3(16,16,6), B256, 0, stream>>>(sa_Wv, WtSv, DD, DD, ZD, ZD, 1.f);
  transpose_cvt<<<dim3(16,16,6), B256, 0, stream>>>(sa_Wo, WtSo, DD, DD, ZD, ZD, 1.f);
  transpose_cvt<<<dim3(16,16,6), B256, 0, stream>>>(ca_Wq, WtCq, DD, DD, ZD, ZD, 0.125f);
  transpose_cvt<<<dim3(16,16,6), B256, 0, stream>>>(ca_Wk, WtCk, DD, DD, ZD, ZD, 1.f);
  transpose_cvt<<<dim3(16,16,6), B256, 0, stream>>>(ca_Wv, WtCv, DD, DD, ZD, ZD, 1.f);
  transpose_cvt<<<dim3(16,16,6), B256, 0, stream>>>(ca_Wo, WtCo, DD, DD, ZD, ZD, 1.f);
  transpose_cvt<<<dim3(32,16,6), B256, 0, stream>>>(ff_W1, WtF1, DD, FFND, (size_t)DD*FFND, (size_t)DD*FFND, 1.f);
  transpose_cvt<<<dim3(16,32,6), B256, 0, stream>>>(ff_W2, WtF2, FFND, DD, (size_t)DD*FFND, (size_t)DD*FFND, 1.f);
  transpose_cvt<<<dim3(8,8,1),  B256, 0, stream>>>(qs_W1, WtQB,      DM, DM, ZM, ZM, 1.f);
  transpose_cvt<<<dim3(8,8,1),  B256, 0, stream>>>(bb_W1, WtQB + ZM, DM, DM, ZM, ZM, 1.f);
  transpose_cvt<<<dim3(8,8,1),  B256, 0, stream>>>(qs_W2, WtQ2, DM, DM, ZM, ZM, 1.f);
  concat_bias<<<dim3(2), B256, 0, stream>>>(qs_b1, bb_b1, QBB);

  // ---------- pre-loop ----------
  init_x<<<dim3((nTotal+255)/256), B256, 0, stream>>>(tgt, query_pos, X, Xb, QIN, nTotal);
  cvt_mem<<<dim3(NMROWS*DD/8/256), B256, 0, stream>>>(memory, pos, MEMb, MEMVb);
  gemm_f32<<<dim3(DM/64, NQROWS/64), B256, 0, stream>>>(query_pos, nullptr, rp_W1, rp_b1, T256, NQROWS, DM, DM, DM, 1);
  gemm_skinny<<<dim3(NQROWS/4), B256, 0, stream>>>(T256, rp_W2, rp_b2, REFB, NQROWS, 2, DM, DM);
  sine_embed_kernel<<<dim3((NQROWS*DM+255)/256), B256, 0, stream>>>(REFB, SINE);

  const int nredu = (128*QLEN + 3) / 4;
  const int qtiles = (QLEN + 63) / 64;
  for (int l = 0; l < 6; ++l) {
    const size_t wo = (size_t)l*DD*DD, fo = (size_t)l*DD*FFND;
    const float* fb1 = ff_b1 + (size_t)l*FFND;
    const float* fb2 = ff_b2 + (size_t)l*DD;

    // fused qs1 (bf16 out) + bbox1 (f32 out), both ReLU, input Xb[:,256:]
    gemm_mfma_split<<<dim3(8, NQROWS/64), B256, 0, stream>>>(Xb+DM, WtQB, QBB, T256b, T256, NQROWS, 512, DM, DD);
    gemm2<32,0,false><<<dim3(DM/128, NQROWS/32), B256, 0, stream>>>(T256b, WtQ2, qs_b2, PT, NQROWS, DM, DM, DM, 0);
    gemm_skinny<<<dim3(NQROWS/4), B256, 0, stream>>>(T256, bb_W2, bb_b2, T4, NQROWS, 4, DM, DM);
    boxes_kernel<<<dim3((NQROWS+255)/256), B256, 0, stream>>>(T4, REFB, BOX, CS);
    bias_kernel<<<dim3((BATCH*QLEN*QLEN+255)/256), B256, 0, stream>>>(BOX, CS, BIAS);

    // ---- self-attention (QIN written by init_x / previous ln3) ----
    gemm2<64,2,false><<<dim3(1024/128, NQROWS/64), B256, 0, stream>>>(QIN, WtSqk + (size_t)l*2*ZD, nullptr, QKb, NQROWS, 1024, DD, DD, QLEN);
    gemm2_vt<64><<<dim3(DD/128, BATCH*5), B256, 0, stream>>>(Xb, WtSv+wo, VTsa, QLEN, DD, DD, SAKPAD, 5);
    attn2<true,true,2><<<dim3(128, qtiles, 2), B256, 0, stream>>>(QKb, QKb, VTsa, BIAS, nullptr, OPARTU, ML, QLEN, QLEN, SAKPAD, 16, 16, 8);
    attn_reduce<2><<<dim3(nredu), B256, 0, stream>>>(OPARTU, ML, AOb, QLEN);
    gemm2<32,0,false><<<dim3(DD/128, NQROWS/32), B256, 0, stream>>>(AOb, WtSo+wo, nullptr, RES, NQROWS, DD, DD, DD, 0);
    ln_residual_t<2><<<dim3(NQROWS), B256, 0, stream>>>(X, RES, Xb, query_pos, SINE, PT, QIN);

    // ---- cross-attention (QIN written by ln1 above) ----
    gemm2<32,2,false><<<dim3(DD/128, NQROWS/32), B256, 0, stream>>>(QIN, WtCq+wo, nullptr, PQb, NQROWS, DD, DD, DD, QLEN);
    gemm2<128,2,false><<<dim3(DD/128, NMROWS/128), B256, 0, stream>>>(MEMb,  WtCk+wo, nullptr, PKb, NMROWS, DD, DD, DD, SLEN);
    gemm2_vt<128><<<dim3(DD/128, BATCH*8), B256, 0, stream>>>(MEMVb, WtCv+wo, PVb, SLEN, DD, DD, SLEN, 8);
    attn2<false,false,2><<<dim3(128, qtiles, 2), B256, 0, stream>>>(PQb, PKb, PVb, nullptr, nullptr, OPARTU, ML, QLEN, SLEN, SLEN, 8, 8, 0);
    attn_reduce<2><<<dim3(nredu), B256, 0, stream>>>(OPARTU, ML, AOb, QLEN);
    gemm2<32,0,false><<<dim3(DD/128, NQROWS/32), B256, 0, stream>>>(AOb, WtCo+wo, nullptr, RES, NQROWS, DD, DD, DD, 0);
    ln_residual_t<0><<<dim3(NQROWS), B256, 0, stream>>>(X, RES, Xb, nullptr, nullptr, nullptr, nullptr);

    // ---- FFN ----
    gemm2<64,1,true ><<<dim3(FFND/128, NQROWS/64), B256, 0, stream>>>(Xb, WtF1+fo, fb1, HIDb, NQROWS, FFND, DD, DD, 0);
    gemm2<32,0,false><<<dim3(DD/128, NQROWS/32), B256, 0, stream>>>(HIDb, WtF2+fo, fb2, RES, NQROWS, DD, FFND, FFND, 0);
    ln_residual_t<1><<<dim3(NQROWS), B256, 0, stream>>>(X, RES, Xb, query_pos, nullptr, nullptr, QIN);
  }

  copy_f32<<<dim3((nTotal+255)/256), B256, 0, stream>>>(X, (float*)d_out, out_size);
}

// Round 12
// 1510.414 us; speedup vs baseline: 1.0669x; 1.0410x over previous
//
#include <hip/hip_runtime.h>
#include <cmath>

#define QLEN 300
#define BATCH 16
#define SLEN 1024
#define DM 256
#define DD 512
#define FFND 1024
#define NQROWS (QLEN*BATCH)   // 4800
#define NMROWS (SLEN*BATCH)   // 16384
#define LQPAD 304
#define SAKPAD 320
#define LOG2E 1.4426950408889634f

typedef __attribute__((ext_vector_type(8))) short short8;
typedef __attribute__((ext_vector_type(4))) float f32x4;
typedef __attribute__((ext_vector_type(4))) unsigned short ushort4_;

__device__ __forceinline__ float sigmoidf_(float x){ return 1.f/(1.f+expf(-x)); }

__device__ __forceinline__ unsigned short f2bf(float x){
  unsigned u = __float_as_uint(x);
  unsigned r = (u + 0x7FFFu + ((u >> 16) & 1u)) >> 16;
  return (unsigned short)r;
}
__device__ __forceinline__ float bf2f(unsigned short u){
  return __uint_as_float(((unsigned)u) << 16);
}

// async global->LDS, 16B per lane; dest = wave-uniform base + lane*16
__device__ __forceinline__ void gload16(const void* g, void* l) {
  __builtin_amdgcn_global_load_lds((const __attribute__((address_space(1))) unsigned int*)g,
                                   (__attribute__((address_space(3))) unsigned int*)l, 16, 0, 0);
}

// ========== weight transpose + f32->bf16 (+scale) : W[K,N] -> Wt[N,K] ==========
__global__ __launch_bounds__(256) void transpose_cvt(
    const float* __restrict__ W, unsigned short* __restrict__ Wt, int K, int N,
    size_t zsrc, size_t zdst, float scale)
{
  __shared__ float T[32][33];
  int n0 = blockIdx.x*32, k0 = blockIdx.y*32;
  size_t zs = (size_t)blockIdx.z * zsrc;
  size_t zd = (size_t)blockIdx.z * zdst;
  int tx = threadIdx.x & 31, ty = threadIdx.x >> 5;
  #pragma unroll
  for (int j = 0; j < 32; j += 8)
    T[ty+j][tx] = W[zs + (size_t)(k0+ty+j)*N + n0+tx];
  __syncthreads();
  #pragma unroll
  for (int j = 0; j < 32; j += 8)
    Wt[zd + (size_t)(n0+ty+j)*K + k0+tx] = f2bf(T[tx][ty+j] * scale);
}

__global__ void concat_bias(const float* __restrict__ b1, const float* __restrict__ b2,
                            float* __restrict__ out)
{
  int i = blockIdx.x*256 + threadIdx.x;
  if (i < 256) out[i] = b1[i];
  else if (i < 512) out[i] = b2[i-256];
}

// ================= gemm2: pipelined bf16 MFMA GEMM, BN=128, BK=64 =================
// C = act(A @ Wt^T + bias). A bf16 [M,lda]; Wt bf16 [N,K].
// OUTMODE 0: f32 [M,N]; 1: bf16 [M,N];
// OUTMODE 2: bf16 head rows [(b*(N/64)+h)*Laux + q][64]  (rowg = q*16+b)
template<int BM, int OUTMODE, bool RELU>
__global__ __launch_bounds__(256) void gemm2(
    const unsigned short* __restrict__ Ab, const unsigned short* __restrict__ Wt,
    const float* __restrict__ bias, void* __restrict__ Cptr,
    int M, int N, int K, int lda, int Laux)
{
  __shared__ __align__(16) unsigned short As[2][BM*64];
  __shared__ __align__(16) unsigned short Bs[2][128*64];
  const int tid = threadIdx.x;
  const int w = tid >> 6, lane = tid & 63;
  const int bm = blockIdx.y*BM, bn = blockIdx.x*128;
  const int wm = w >> 1, wn = w & 1;
  const int c = lane & 15, hi = lane >> 4;
  constexpr int MR = (BM + 31)/32 < 1 ? 1 : BM/32;
  f32x4 acc[MR < 1 ? 1 : MR][4] = {};
  const int lrow8 = lane >> 3;
  const int lcol  = ((lane & 7) ^ lrow8) << 3;
  const int nt = K >> 6;

  auto stage = [&](int buf, int k0) {
    #pragma unroll
    for (int it = 0; it < BM/32; ++it) {
      int r = it*32 + w*8;
      gload16(&Ab[(size_t)(bm + r + lrow8)*lda + k0 + lcol], &As[buf][r*64]);
    }
    #pragma unroll
    for (int it = 0; it < 4; ++it) {
      int r = it*32 + w*8;
      gload16(&Wt[(size_t)(bn + r + lrow8)*K + k0 + lcol], &Bs[buf][r*64]);
    }
  };

  stage(0, 0);
  for (int t = 0; t < nt; ++t) {
    const int cur = t & 1;
    if (t + 1 < nt) {
      stage(cur ^ 1, (t+1) << 6);
      if constexpr (BM == 32)      asm volatile("s_waitcnt vmcnt(5)" ::: "memory");
      else if constexpr (BM == 64) asm volatile("s_waitcnt vmcnt(6)" ::: "memory");
      else                         asm volatile("s_waitcnt vmcnt(8)" ::: "memory");
    } else {
      asm volatile("s_waitcnt vmcnt(0)" ::: "memory");
    }
    __builtin_amdgcn_s_barrier();
    #pragma unroll
    for (int ks = 0; ks < 2; ++ks) {
      short8 a[MR], bf[4];
      #pragma unroll
      for (int mr = 0; mr < MR; ++mr) {
        int m = wm*(BM/2) + mr*16 + c;
        a[mr] = *reinterpret_cast<const short8*>(&As[cur][m*64 + ((ks*32 + hi*8) ^ ((m&7)<<3))]);
      }
      #pragma unroll
      for (int nr = 0; nr < 4; ++nr) {
        int n = wn*64 + nr*16 + c;
        bf[nr] = *reinterpret_cast<const short8*>(&Bs[cur][n*64 + ((ks*32 + hi*8) ^ ((n&7)<<3))]);
      }
      #pragma unroll
      for (int mr = 0; mr < MR; ++mr)
        #pragma unroll
        for (int nr = 0; nr < 4; ++nr)
          acc[mr][nr] = __builtin_amdgcn_mfma_f32_16x16x32_bf16(a[mr], bf[nr], acc[mr][nr], 0, 0, 0);
    }
    asm volatile("s_waitcnt lgkmcnt(0)" ::: "memory");
    __builtin_amdgcn_sched_barrier(0);
    __builtin_amdgcn_s_barrier();
  }
  const int hs = N >> 6;
  #pragma unroll
  for (int mr = 0; mr < MR; ++mr) {
    #pragma unroll
    for (int nr = 0; nr < 4; ++nr) {
      int colg = bn + wn*64 + nr*16 + c;
      float bv = bias ? bias[colg] : 0.f;
      #pragma unroll
      for (int r = 0; r < 4; ++r) {
        int rowg = bm + wm*(BM/2) + mr*16 + hi*4 + r;
        float v = acc[mr][nr][r] + bv;
        if (RELU) v = fmaxf(v, 0.f);
        if (OUTMODE == 0) {
          ((float*)Cptr)[(size_t)rowg*N + colg] = v;
        } else if (OUTMODE == 1) {
          ((unsigned short*)Cptr)[(size_t)rowg*N + colg] = f2bf(v);
        } else {
          int bb = rowg & 15, row = rowg >> 4, h = colg >> 6, dl = colg & 63;
          ((unsigned short*)Cptr)[(((size_t)bb*hs + h)*Laux + row)*64 + dl] = f2bf(v);
        }
      }
    }
  }
}

// ================= gemm2_vt: V-projection producing V^T, per-batch tiles ==========
template<int BM>
__global__ __launch_bounds__(256) void gemm2_vt(
    const unsigned short* __restrict__ Ab, const unsigned short* __restrict__ Wt,
    unsigned short* __restrict__ VT, int Lsrc, int K, int lda, int Lkpad, int tilesPerB)
{
  __shared__ __align__(16) unsigned short As[2][BM*64];
  __shared__ __align__(16) unsigned short Bs[2][128*64];
  const int tid = threadIdx.x;
  const int w = tid >> 6, lane = tid & 63;
  const int b = blockIdx.y / tilesPerB;
  const int qt = (blockIdx.y - b*tilesPerB) * BM;
  const int bn = blockIdx.x*128;
  const int wm = w >> 1, wn = w & 1;
  const int c = lane & 15, hi = lane >> 4;
  constexpr int MR = BM/32;
  f32x4 acc[MR][4] = {};
  const int lrow8 = lane >> 3;
  const int lcol  = ((lane & 7) ^ lrow8) << 3;
  const int nt = K >> 6;

  auto stage = [&](int buf, int k0) {
    #pragma unroll
    for (int it = 0; it < BM/32; ++it) {
      int r = it*32 + w*8;
      int q = qt + r + lrow8; if (q > Lsrc-1) q = Lsrc-1;
      gload16(&Ab[(size_t)(q*BATCH + b)*lda + k0 + lcol], &As[buf][r*64]);
    }
    #pragma unroll
    for (int it = 0; it < 4; ++it) {
      int r = it*32 + w*8;
      gload16(&Wt[(size_t)(bn + r + lrow8)*K + k0 + lcol], &Bs[buf][r*64]);
    }
  };

  stage(0, 0);
  for (int t = 0; t < nt; ++t) {
    const int cur = t & 1;
    if (t + 1 < nt) {
      stage(cur ^ 1, (t+1) << 6);
      if constexpr (BM == 64) asm volatile("s_waitcnt vmcnt(6)" ::: "memory");
      else                    asm volatile("s_waitcnt vmcnt(8)" ::: "memory");
    } else {
      asm volatile("s_waitcnt vmcnt(0)" ::: "memory");
    }
    __builtin_amdgcn_s_barrier();
    #pragma unroll
    for (int ks = 0; ks < 2; ++ks) {
      short8 a[MR], bf[4];
      #pragma unroll
      for (int mr = 0; mr < MR; ++mr) {
        int m = wm*(BM/2) + mr*16 + c;
        a[mr] = *reinterpret_cast<const short8*>(&As[cur][m*64 + ((ks*32 + hi*8) ^ ((m&7)<<3))]);
      }
      #pragma unroll
      for (int nr = 0; nr < 4; ++nr) {
        int n = wn*64 + nr*16 + c;
        bf[nr] = *reinterpret_cast<const short8*>(&Bs[cur][n*64 + ((ks*32 + hi*8) ^ ((n&7)<<3))]);
      }
      #pragma unroll
      for (int mr = 0; mr < MR; ++mr)
        #pragma unroll
        for (int nr = 0; nr < 4; ++nr)
          acc[mr][nr] = __builtin_amdgcn_mfma_f32_16x16x32_bf16(a[mr], bf[nr], acc[mr][nr], 0, 0, 0);
    }
    asm volatile("s_waitcnt lgkmcnt(0)" ::: "memory");
    __builtin_amdgcn_sched_barrier(0);
    __builtin_amdgcn_s_barrier();
  }
  #pragma unroll
  for (int mr = 0; mr < MR; ++mr) {
    #pragma unroll
    for (int nr = 0; nr < 4; ++nr) {
      int colg = bn + wn*64 + nr*16 + c;
      int h = colg >> 6, dl = colg & 63;
      int q0 = qt + wm*(BM/2) + mr*16 + hi*4;
      ushort4_ pack;
      #pragma unroll
      for (int r = 0; r < 4; ++r) pack[r] = f2bf(acc[mr][nr][r]);
      *reinterpret_cast<ushort4_*>(&VT[((size_t)(b*8 + h)*64 + dl)*Lkpad + q0]) = pack;
    }
  }
}

// ===== fused qs1+bbox1: A bf16 [M,lda]; N=512 (cols 0..255 -> bf16 C1, 256..511 -> f32 C2), ReLU =====
__global__ __launch_bounds__(256) void gemm_mfma_split(
    const unsigned short* __restrict__ Ab, const unsigned short* __restrict__ Wt,
    const float* __restrict__ bias, unsigned short* __restrict__ C1, float* __restrict__ C2,
    int M, int N, int K, int lda)
{
  __shared__ __align__(16) unsigned short As[64][72];
  __shared__ __align__(16) unsigned short Bs[64][72];
  const int tid = threadIdx.x;
  const int bm = blockIdx.y*64, bn = blockIdx.x*64;
  const int w = tid >> 6, lane = tid & 63;
  const int wm = w >> 1, wn = w & 1;
  const int c = lane & 15, hi = lane >> 4;
  const int sr = tid >> 3, sk = (tid & 7) * 8;
  f32x4 acc[2][2] = {};
  for (int k0 = 0; k0 < K; k0 += 64) {
    #pragma unroll
    for (int it = 0; it < 2; ++it) {
      int m = sr + it*32;
      short8 v = *reinterpret_cast<const short8*>(&Ab[(size_t)(bm+m)*lda + k0 + sk]);
      *reinterpret_cast<short8*>(&As[m][sk]) = v;
      short8 bv = *reinterpret_cast<const short8*>(&Wt[(size_t)(bn+m)*K + k0 + sk]);
      *reinterpret_cast<short8*>(&Bs[m][sk]) = bv;
    }
    __syncthreads();
    #pragma unroll
    for (int ks = 0; ks < 2; ++ks) {
      short8 a0 = *reinterpret_cast<const short8*>(&As[wm*32 + c][ks*32 + hi*8]);
      short8 a1 = *reinterpret_cast<const short8*>(&As[wm*32 + 16 + c][ks*32 + hi*8]);
      short8 b0 = *reinterpret_cast<const short8*>(&Bs[wn*32 + c][ks*32 + hi*8]);
      short8 b1 = *reinterpret_cast<const short8*>(&Bs[wn*32 + 16 + c][ks*32 + hi*8]);
      acc[0][0] = __builtin_amdgcn_mfma_f32_16x16x32_bf16(a0, b0, acc[0][0], 0, 0, 0);
      acc[0][1] = __builtin_amdgcn_mfma_f32_16x16x32_bf16(a0, b1, acc[0][1], 0, 0, 0);
      acc[1][0] = __builtin_amdgcn_mfma_f32_16x16x32_bf16(a1, b0, acc[1][0], 0, 0, 0);
      acc[1][1] = __builtin_amdgcn_mfma_f32_16x16x32_bf16(a1, b1, acc[1][1], 0, 0, 0);
    }
    __syncthreads();
  }
  #pragma unroll
  for (int mf = 0; mf < 2; ++mf) {
    #pragma unroll
    for (int nf = 0; nf < 2; ++nf) {
      int colg = bn + wn*32 + nf*16 + c;
      float bv = bias[colg];
      #pragma unroll
      for (int r = 0; r < 4; ++r) {
        int rowg = bm + wm*32 + mf*16 + hi*4 + r;
        float v = fmaxf(acc[mf][nf][r] + bv, 0.f);
        if (colg < 256) C1[(size_t)rowg*256 + colg] = f2bf(v);
        else            C2[(size_t)rowg*256 + (colg-256)] = v;
      }
    }
  }
}

// ================= attn2: pipelined MFMA flash attention (swapped QK^T, exp2 units) ==
// Q rows at (b*qmul + h)*Lq (Wq pre-scaled by 0.125*log2e); K rows at (b*kmul+koff+h)*Lk;
// bias pre-scaled by log2e. VT [(b*8+h)*64+d][Lkpad]. Defer-rescale THR=8*log2e.
// Pl swizzled (no pad): 16B chunk ^= (c&7); LDS = 40960 B.
template<bool HAS_BIAS, bool MASK, int NS>
__global__ __launch_bounds__(256) void attn2(
    const unsigned short* __restrict__ Qh, const unsigned short* __restrict__ Kh,
    const unsigned short* __restrict__ VT, const float* __restrict__ bias,
    unsigned short* __restrict__ Ob, unsigned short* __restrict__ Opart, float* __restrict__ MLpart,
    int Lq, int Lk, int Lkpad, int qmul, int kmul, int koff)
{
  __shared__ __align__(16) unsigned short Ks[2][64*64];
  __shared__ __align__(16) unsigned short Vs[2][64*64];
  __shared__ __align__(16) unsigned short Pl[4][16*64];
  const int tid = threadIdx.x;
  const int w = tid >> 6, lane = tid & 63;
  const int c = lane & 15, hi = lane >> 4;
  const int bh = blockIdx.x;
  const int qt = blockIdx.y * 64;
  const int sp = blockIdx.z;
  const int b = bh >> 3, h = bh & 7;
  const int lrow8 = lane >> 3;
  const int lcol  = ((lane & 7) ^ lrow8) << 3;

  const int nt_tot = (Lk + 63) >> 6;
  const int t0 = (nt_tot * sp) / NS;
  const int t1 = (nt_tot * (sp + 1)) / NS;

  int qrow = qt + w*16 + c; if (qrow > Lq-1) qrow = Lq-1;
  const unsigned short* qptr = Qh + ((size_t)(b*qmul + h)*Lq + qrow)*64;
  short8 qf0 = *reinterpret_cast<const short8*>(qptr + hi*8);
  short8 qf1 = *reinterpret_cast<const short8*>(qptr + 32 + hi*8);
  const size_t kbase = (size_t)(b*kmul + koff + h)*Lk;

  float m_ = -1e30f, l_ = 0.f;
  f32x4 accO[4] = {};
  const int qbase = qt + w*16 + hi*4;

  auto stageKV = [&](int buf, int kt) {
    #pragma unroll
    for (int it = 0; it < 2; ++it) {
      int r = it*32 + w*8;
      int kr = kt + r + lrow8; if (MASK && kr > Lk-1) kr = Lk-1;
      gload16(&Kh[(kbase + kr)*64 + lcol], &Ks[buf][r*64]);
    }
    #pragma unroll
    for (int it = 0; it < 2; ++it) {
      int r = it*32 + w*8;
      gload16(&VT[((size_t)bh*64 + r + lrow8)*Lkpad + kt + lcol], &Vs[buf][r*64]);
    }
  };

  stageKV(0, t0 << 6);
  for (int t = t0; t < t1; ++t) {
    const int cur = (t - t0) & 1;
    const int kt = t << 6;
    float4 bs4[4];
    if (HAS_BIAS) {
      #pragma unroll
      for (int g = 0; g < 4; ++g)
        bs4[g] = *reinterpret_cast<const float4*>(
            &bias[((size_t)b*Lq + qrow)*Lk + kt + g*16 + hi*4]);
    }
    if (t + 1 < t1) {
      stageKV(cur ^ 1, (t+1) << 6);
      asm volatile("s_waitcnt vmcnt(4)" ::: "memory");
    } else {
      asm volatile("s_waitcnt vmcnt(0)" ::: "memory");
    }
    __builtin_amdgcn_s_barrier();
    // ---- S^T = K Q^T  (log2e & 1/8 folded into Q projection) ----
    f32x4 s[4] = {};
    __builtin_amdgcn_s_setprio(1);
    #pragma unroll
    for (int g = 0; g < 4; ++g) {
      int m = g*16 + c;
      short8 kb0 = *reinterpret_cast<const short8*>(&Ks[cur][m*64 + ((hi*8)      ^ ((m&7)<<3))]);
      short8 kb1 = *reinterpret_cast<const short8*>(&Ks[cur][m*64 + ((32 + hi*8) ^ ((m&7)<<3))]);
      s[g] = __builtin_amdgcn_mfma_f32_16x16x32_bf16(kb0, qf0, s[g], 0, 0, 0);
      s[g] = __builtin_amdgcn_mfma_f32_16x16x32_bf16(kb1, qf1, s[g], 0, 0, 0);
    }
    __builtin_amdgcn_s_setprio(0);
    // ---- logits + lane-local online softmax (base-2) ----
    float tmax = -1e30f;
    #pragma unroll
    for (int g = 0; g < 4; ++g) {
      #pragma unroll
      for (int r = 0; r < 4; ++r) {
        float v = s[g][r];
        if (HAS_BIAS) v += ((const float*)&bs4[g])[r];
        if (MASK && (kt + g*16 + hi*4 + r >= Lk)) v = -1e30f;
        s[g][r] = v;
        tmax = fmaxf(tmax, v);
      }
    }
    tmax = fmaxf(tmax, __shfl_xor(tmax, 16));
    tmax = fmaxf(tmax, __shfl_xor(tmax, 32));
    // T13 defer-rescale: skip when growth <= 8*log2e (P bounded by 2^11.54)
    if (!__all(tmax - m_ <= 11.5416f)) {
      float newm = fmaxf(m_, tmax);
      float corr = exp2f(m_ - newm);
      m_ = newm;
      l_ *= corr;
      float corr4[4];
      #pragma unroll
      for (int r = 0; r < 4; ++r) corr4[r] = __shfl(corr, hi*4 + r);
      #pragma unroll
      for (int dg = 0; dg < 4; ++dg)
        #pragma unroll
        for (int r = 0; r < 4; ++r) accO[dg][r] *= corr4[r];
    }
    float psum = 0.f;
    #pragma unroll
    for (int g = 0; g < 4; ++g) {
      ushort4_ pp;
      #pragma unroll
      for (int r = 0; r < 4; ++r) {
        float e = exp2f(s[g][r] - m_);
        psum += e;
        pp[r] = f2bf(e);
      }
      // write P[q=c][keys g*16+hi*4..+3]: chunk (2g|(hi>>1)) ^ (c&7), half (hi&1)
      int idx = c*64 + ((((g<<1)|(hi>>1)) ^ (c&7))<<3) + ((hi&1)<<2);
      *reinterpret_cast<ushort4_*>(&Pl[w][idx]) = pp;
    }
    psum += __shfl_xor(psum, 16);
    psum += __shfl_xor(psum, 32);
    l_ += psum;
    // ---- O += P V ----
    __builtin_amdgcn_s_setprio(1);
    #pragma unroll
    for (int ks = 0; ks < 2; ++ks) {
      // read P[q=c][keys ks*32+hi*8..+7]: chunk (ks*4+hi) ^ (c&7)
      short8 pa = *reinterpret_cast<const short8*>(&Pl[w][c*64 + ((((ks<<2)|hi) ^ (c&7))<<3)]);
      #pragma unroll
      for (int dg = 0; dg < 4; ++dg) {
        int n = dg*16 + c;
        short8 vb = *reinterpret_cast<const short8*>(&Vs[cur][n*64 + ((ks*32 + hi*8) ^ ((n&7)<<3))]);
        accO[dg] = __builtin_amdgcn_mfma_f32_16x16x32_bf16(pa, vb, accO[dg], 0, 0, 0);
      }
    }
    __builtin_amdgcn_s_setprio(0);
    asm volatile("s_waitcnt lgkmcnt(0)" ::: "memory");
    __builtin_amdgcn_sched_barrier(0);
    __builtin_amdgcn_s_barrier();
  }
  // ---- epilogue ----
  if (NS == 1) {
    float l4[4];
    #pragma unroll
    for (int r = 0; r < 4; ++r) l4[r] = __shfl(l_, hi*4 + r);
    #pragma unroll
    for (int r = 0; r < 4; ++r) {
      int qg = qbase + r;
      if (qg < Lq) {
        float inv = 1.f / l4[r];
        #pragma unroll
        for (int dg = 0; dg < 4; ++dg)
          Ob[((size_t)qg*BATCH + b)*DD + h*64 + 16*dg + c] = f2bf(accO[dg][r] * inv);
      }
    }
  } else {
    int qc = qt + w*16 + c;
    if (hi == 0 && qc < Lq) {
      size_t rowml = ((size_t)sp*128 + bh)*LQPAD + qc;
      MLpart[rowml*2]     = m_;
      MLpart[rowml*2 + 1] = l_;
    }
    #pragma unroll
    for (int r = 0; r < 4; ++r) {
      int qg = qbase + r;
      if (qg < Lq) {
        size_t rowo = ((size_t)sp*128 + bh)*LQPAD + qg;
        #pragma unroll
        for (int dg = 0; dg < 4; ++dg)
          Opart[rowo*64 + dg*16 + c] = f2bf(accO[dg][r]);
      }
    }
  }
}

// combine NSR partials (m in log2 units) -> bf16 out [q*16+b][512]
template<int NSR>
__global__ __launch_bounds__(256) void attn_reduce(
    const unsigned short* __restrict__ Opart, const float* __restrict__ MLpart,
    unsigned short* __restrict__ Ob, int Lq)
{
  int w = threadIdx.x >> 6, lane = threadIdx.x & 63;
  int pair = blockIdx.x*4 + w;
  if (pair >= 128*Lq) return;
  int bh = pair / Lq, q = pair - bh*Lq;
  size_t rr[NSR];
  float m[NSR], l[NSR], M = -1e30f;
  #pragma unroll
  for (int s = 0; s < NSR; ++s) {
    rr[s] = ((size_t)s*128 + bh)*LQPAD + q;
    m[s] = MLpart[rr[s]*2];
    l[s] = MLpart[rr[s]*2 + 1];
    M = fmaxf(M, m[s]);
  }
  float o = 0.f, L = 0.f;
  #pragma unroll
  for (int s = 0; s < NSR; ++s) {
    float wg = exp2f(m[s] - M);
    o += wg * bf2f(Opart[rr[s]*64 + lane]);
    L += wg * l[s];
  }
  int b = bh >> 3, h = bh & 7;
  Ob[((size_t)q*BATCH + b)*DD + h*64 + lane] = f2bf(o / L);
}

// ================= f32 GEMM (pre-loop rp MLP only) =================
__global__ __launch_bounds__(256) void gemm_f32(
    const float* __restrict__ A, const float* __restrict__ A2,
    const float* __restrict__ W, const float* __restrict__ bias,
    float* __restrict__ C, int M, int N, int K, int lda, int relu)
{
  __shared__ __align__(16) float As[16][68];
  __shared__ __align__(16) float Bs[16][68];
  const int tid = threadIdx.x;
  const int bm = blockIdx.y * 64, bn = blockIdx.x * 64;
  const int tx = tid & 15, ty = tid >> 4;
  const int ar = tid >> 4, ac = tid & 15;
  const int bk = tid >> 6, bnn = tid & 63;
  float acc[4][4] = {};
  for (int k0 = 0; k0 < K; k0 += 16) {
    #pragma unroll
    for (int i = 0; i < 4; ++i) {
      int row = ar + i*16;
      float v = A[(size_t)(bm+row)*lda + (k0+ac)];
      if (A2) v += A2[(size_t)(bm+row)*lda + (k0+ac)];
      As[ac][row] = v;
    }
    #pragma unroll
    for (int i = 0; i < 4; ++i) {
      int kk = bk + i*4;
      Bs[kk][bnn] = W[(size_t)(k0+kk)*N + (bn+bnn)];
    }
    __syncthreads();
    #pragma unroll
    for (int k = 0; k < 16; ++k) {
      float4 a4 = *reinterpret_cast<const float4*>(&As[k][ty*4]);
      float4 b4 = *reinterpret_cast<const float4*>(&Bs[k][tx*4]);
      float a[4] = {a4.x,a4.y,a4.z,a4.w};
      float bb[4] = {b4.x,b4.y,b4.z,b4.w};
      #pragma unroll
      for (int i=0;i<4;++i)
        #pragma unroll
        for (int j=0;j<4;++j)
          acc[i][j] = fmaf(a[i], bb[j], acc[i][j]);
    }
    __syncthreads();
  }
  float vb[4] = {0.f,0.f,0.f,0.f};
  if (bias) {
    float4 b4 = *reinterpret_cast<const float4*>(&bias[bn + tx*4]);
    vb[0]=b4.x; vb[1]=b4.y; vb[2]=b4.z; vb[3]=b4.w;
  }
  #pragma unroll
  for (int i=0;i<4;++i) {
    int row = bm + ty*4 + i;
    float r0 = acc[i][0]+vb[0], r1 = acc[i][1]+vb[1], r2 = acc[i][2]+vb[2], r3 = acc[i][3]+vb[3];
    if (relu){ r0=fmaxf(r0,0.f); r1=fmaxf(r1,0.f); r2=fmaxf(r2,0.f); r3=fmaxf(r3,0.f); }
    float4 o; o.x=r0; o.y=r1; o.z=r2; o.w=r3;
    *reinterpret_cast<float4*>(&C[(size_t)row*N + bn + tx*4]) = o;
  }
}

// rp MLP final layer (N=2): plain skinny
__global__ __launch_bounds__(256) void gemm_skinny(
    const float* __restrict__ A, const float* __restrict__ W, const float* __restrict__ bias,
    float* __restrict__ C, int M, int N, int K, int lda)
{
  int wid = threadIdx.x >> 6, lane = threadIdx.x & 63;
  int row = blockIdx.x * 4 + wid;
  if (row >= M) return;
  float acc[4] = {0.f,0.f,0.f,0.f};
  for (int k = lane; k < K; k += 64) {
    float av = A[(size_t)row*lda + k];
    for (int n = 0; n < N; ++n) acc[n] += av * W[(size_t)k*N + n];
  }
  for (int off = 32; off; off >>= 1)
    for (int n = 0; n < N; ++n) acc[n] += __shfl_down(acc[n], off);
  if (lane == 0)
    for (int n = 0; n < N; ++n) C[(size_t)row*N + n] = acc[n] + bias[n];
}

// bbox final layer (N=4) fused with boxes/cs epilogue
__global__ __launch_bounds__(256) void gemm_skinny_boxes(
    const float* __restrict__ A, const float* __restrict__ W, const float* __restrict__ bias,
    const float* __restrict__ refb, float* __restrict__ boxes, float* __restrict__ cs,
    int M, int K, int lda)
{
  int wid = threadIdx.x >> 6, lane = threadIdx.x & 63;
  int row = blockIdx.x * 4 + wid;
  if (row >= M) return;
  float acc[4] = {0.f,0.f,0.f,0.f};
  for (int k = lane; k < K; k += 64) {
    float av = A[(size_t)row*lda + k];
    #pragma unroll
    for (int n = 0; n < 4; ++n) acc[n] += av * W[(size_t)k*4 + n];
  }
  for (int off = 32; off; off >>= 1)
    #pragma unroll
    for (int n = 0; n < 4; ++n) acc[n] += __shfl_down(acc[n], off);
  if (lane == 0) {
    int q = row / BATCH, b = row - q*BATCH;
    float cx = sigmoidf_(acc[0] + bias[0] + refb[row*2+0]);
    float cy = sigmoidf_(acc[1] + bias[1] + refb[row*2+1]);
    float w_ = sigmoidf_(acc[2] + bias[2]);
    float h_ = sigmoidf_(acc[3] + bias[3]);
    int o = b*QLEN + q;
    boxes[o*4+0] = cx - 0.5f*w_;
    boxes[o*4+1] = cy - 0.5f*h_;
    boxes[o*4+2] = cx + 0.5f*w_;
    boxes[o*4+3] = cy + 0.5f*h_;
    cs[o] = cx + cy;
  }
}

__global__ void sine_embed_kernel(const float* __restrict__ refb, float* __restrict__ sine)
{
  int idx = blockIdx.x*blockDim.x + threadIdx.x;
  if (idx >= NQROWS*DM) return;
  int r = idx >> 8, c = idx & 255;
  int j = c & 127;
  float coord = refb[r*2 + (c < 128 ? 1 : 0)];
  float s = sigmoidf_(coord);
  float freq = expf(-(float)(j >> 1) * (9.210340371976184f / 64.f));
  float v = s * 6.283185307179586f * freq;
  sine[idx] = (j & 1) ? cosf(v) : sinf(v);
}

// bias[b,i,j] = (IoU + order) * log2e  (exp2-unit softmax downstream)
__global__ void bias_kernel(const float* __restrict__ boxes, const float* __restrict__ cs,
                            float* __restrict__ bias)
{
  int idx = blockIdx.x*blockDim.x + threadIdx.x;
  const int QQ = QLEN*QLEN;
  if (idx >= BATCH*QQ) return;
  int b = idx / QQ, rem = idx - b*QQ;
  int i = rem / QLEN, j = rem - i*QLEN;
  float4 bi = *reinterpret_cast<const float4*>(&boxes[((size_t)b*QLEN + i)*4]);
  float4 bj = *reinterpret_cast<const float4*>(&boxes[((size_t)b*QLEN + j)*4]);
  float ai = (bi.z-bi.x)*(bi.w-bi.y);
  float aj = (bj.z-bj.x)*(bj.w-bj.y);
  float ltx = fmaxf(bi.x, bj.x), lty = fmaxf(bi.y, bj.y);
  float rbx = fminf(bi.z, bj.z), rby = fminf(bi.w, bj.w);
  float w = fmaxf(rbx-ltx, 0.f), h = fmaxf(rby-lty, 0.f);
  float inter = w*h;
  float iou = inter / (ai + aj - inter);
  bias[idx] = (iou + ((cs[b*QLEN+i] > cs[b*QLEN+j]) ? 1.f : 0.f)) * LOG2E;
}

// memory / memory+pos -> bf16, once per call (loop-invariant)
__global__ void cvt_mem(const float* __restrict__ mem, const float* __restrict__ pos,
                        unsigned short* __restrict__ mb, unsigned short* __restrict__ mvb)
{
  int i = blockIdx.x*blockDim.x + threadIdx.x;
  if (i >= NMROWS*DD/8) return;
  size_t base = (size_t)i*8;
  float4 a0 = *reinterpret_cast<const float4*>(mem+base);
  float4 a1 = *reinterpret_cast<const float4*>(mem+base+4);
  float4 p0 = *reinterpret_cast<const float4*>(pos+base);
  float4 p1 = *reinterpret_cast<const float4*>(pos+base+4);
  short8 s1, s2;
  s1[0]=(short)f2bf(a0.x+p0.x); s1[1]=(short)f2bf(a0.y+p0.y); s1[2]=(short)f2bf(a0.z+p0.z); s1[3]=(short)f2bf(a0.w+p0.w);
  s1[4]=(short)f2bf(a1.x+p1.x); s1[5]=(short)f2bf(a1.y+p1.y); s1[6]=(short)f2bf(a1.z+p1.z); s1[7]=(short)f2bf(a1.w+p1.w);
  s2[0]=(short)f2bf(a0.x); s2[1]=(short)f2bf(a0.y); s2[2]=(short)f2bf(a0.z); s2[3]=(short)f2bf(a0.w);
  s2[4]=(short)f2bf(a1.x); s2[5]=(short)f2bf(a1.y); s2[6]=(short)f2bf(a1.z); s2[7]=(short)f2bf(a1.w);
  *reinterpret_cast<short8*>(mb+base)  = s1;
  *reinterpret_cast<short8*>(mvb+base) = s2;
}

// ===== residual + LN, in-place on X, emits bf16 Xb; EMIT 1: QIN=bf16(o+qp2); EMIT 2: QIN=bf16(o+qp2+sine*pt) =====
template<int EMIT>
__global__ __launch_bounds__(256) void ln_residual_t(
    float* __restrict__ X, const float* __restrict__ Y, unsigned short* __restrict__ Xb,
    const float* __restrict__ qp, const float* __restrict__ sine, const float* __restrict__ pt,
    unsigned short* __restrict__ QIN)
{
  int row = blockIdx.x, tid = threadIdx.x;
  size_t base = (size_t)row*DD;
  float v0 = X[base+tid]     + Y[base+tid];
  float v1 = X[base+tid+256] + Y[base+tid+256];
  float s = v0+v1, sq = v0*v0+v1*v1;
  for (int off = 32; off; off >>= 1) { s += __shfl_down(s,off); sq += __shfl_down(sq,off); }
  __shared__ float ss[4], ssq[4];
  int wid = tid>>6, lane = tid&63;
  if (lane==0){ ss[wid]=s; ssq[wid]=sq; }
  __syncthreads();
  if (tid==0){
    float a=ss[0]+ss[1]+ss[2]+ss[3], bsum=ssq[0]+ssq[1]+ssq[2]+ssq[3];
    float mean = a*(1.f/DD);
    float var  = bsum*(1.f/DD) - mean*mean;
    ss[0]=mean; ssq[0]=rsqrtf(fmaxf(var,0.f)+1e-5f);
  }
  __syncthreads();
  float mean = ss[0], inv = ssq[0];
  float o0 = (v0-mean)*inv, o1 = (v1-mean)*inv;
  X[base+tid]     = o0;  Xb[base+tid]     = f2bf(o0);
  X[base+tid+256] = o1;  Xb[base+tid+256] = f2bf(o1);
  if (EMIT >= 1) {
    size_t c2 = (size_t)row*256 + tid;
    float add = qp[c2];
    if (EMIT == 2) add += sine[c2]*pt[c2];
    QIN[base+tid]     = f2bf(o0 + add);
    QIN[base+tid+256] = f2bf(o1 + add);
  }
}

// init: X=tgt, Xb=bf16(tgt), QIN=bf16(tgt+qp2)
__global__ void init_x(const float* __restrict__ t, const float* __restrict__ qp,
                       float* __restrict__ X, unsigned short* __restrict__ Xb,
                       unsigned short* __restrict__ QIN, int n)
{
  int idx = blockIdx.x*blockDim.x + threadIdx.x;
  if (idx < n){
    float v = t[idx]; X[idx]=v; Xb[idx]=f2bf(v);
    int r = idx >> 9, c = idx & 511;
    QIN[idx] = f2bf(v + qp[(r<<8) + (c & 255)]);
  }
}

__global__ void copy_f32(const float* __restrict__ src, float* __restrict__ dst, int n)
{
  int idx = blockIdx.x*blockDim.x + threadIdx.x;
  if (idx < n) dst[idx] = src[idx];
}

extern "C" void kernel_launch(void* const* d_in, const int* in_sizes, int n_in,
                              void* d_out, int out_size, void* d_ws, size_t ws_size,
                              hipStream_t stream)
{
  const float* tgt       = (const float*)d_in[0];
  const float* memory    = (const float*)d_in[1];
  const float* pos       = (const float*)d_in[2];
  const float* query_pos = (const float*)d_in[3];
  const float* qs_W1 = (const float*)d_in[4];  const float* qs_b1 = (const float*)d_in[5];
  const float* qs_W2 = (const float*)d_in[6];  const float* qs_b2 = (const float*)d_in[7];
  const float* rp_W1 = (const float*)d_in[8];  const float* rp_b1 = (const float*)d_in[9];
  const float* rp_W2 = (const float*)d_in[10]; const float* rp_b2 = (const float*)d_in[11];
  const float* bb_W1 = (const float*)d_in[12]; const float* bb_b1 = (const float*)d_in[13];
  const float* bb_W2 = (const float*)d_in[14]; const float* bb_b2 = (const float*)d_in[15];
  const float* sa_Wq = (const float*)d_in[16]; const float* sa_Wk = (const float*)d_in[17];
  const float* sa_Wv = (const float*)d_in[18]; const float* sa_Wo = (const float*)d_in[19];
  const float* ca_Wq = (const float*)d_in[20]; const float* ca_Wk = (const float*)d_in[21];
  const float* ca_Wv = (const float*)d_in[22]; const float* ca_Wo = (const float*)d_in[23];
  const float* ff_W1 = (const float*)d_in[24]; const float* ff_b1 = (const float*)d_in[25];
  const float* ff_W2 = (const float*)d_in[26]; const float* ff_b2 = (const float*)d_in[27];

  // ---------- workspace layout ----------
  float* F = (float*)d_ws;
  size_t o = 0;
  float* X    = F + o; o += (size_t)NQROWS*DD;
  float* RES  = F + o; o += (size_t)NQROWS*DD;
  float* SINE = F + o; o += (size_t)NQROWS*DM;
  float* PT   = F + o; o += (size_t)NQROWS*DM;
  float* BIAS = F + o; o += (size_t)BATCH*QLEN*QLEN;
  float* REFB = F + o; o += (size_t)NQROWS*2;
  float* BOX  = F + o; o += (size_t)NQROWS*4;
  float* CS   = F + o; o += (size_t)NQROWS;
  float* ML   = F + o; o += (size_t)2*128*LQPAD*2;
  float* QBB  = F + o; o += 512;
  float* T256 = RES;   // alias (lifetime-disjoint)
  unsigned short* U = (unsigned short*)(F + o);
  size_t u = 0;
  unsigned short* Xb   = U + u; u += (size_t)NQROWS*DD;
  unsigned short* QIN  = U + u; u += (size_t)NQROWS*DD;
  unsigned short* PQb  = U + u; u += (size_t)NQROWS*DD;     // with PKb: fused SA QK buffer
  unsigned short* PKb  = U + u; u += (size_t)NMROWS*DD;
  unsigned short* PVb  = U + u; u += (size_t)NMROWS*DD;     // CA V^T [128*64][1024]
  unsigned short* VTsa = U + u; u += (size_t)128*64*SAKPAD; // SA V^T [128*64][320]
  unsigned short* OPARTU = U + u; u += (size_t)2*128*LQPAD*64;
  unsigned short* T256b= U + u; u += (size_t)NQROWS*DM;
  unsigned short* MEMb = U + u; u += (size_t)NMROWS*DD;
  unsigned short* MEMVb= U + u; u += (size_t)NMROWS*DD;
  unsigned short* WtSqk= U + u; u += (size_t)6*2*DD*DD;     // fused [1024][512]/layer (Q half pre-scaled)
  unsigned short* WtSv = U + u; u += (size_t)6*DD*DD;
  unsigned short* WtSo = U + u; u += (size_t)6*DD*DD;
  unsigned short* WtCq = U + u; u += (size_t)6*DD*DD;       // pre-scaled by 0.125*log2e
  unsigned short* WtCk = U + u; u += (size_t)6*DD*DD;
  unsigned short* WtCv = U + u; u += (size_t)6*DD*DD;
  unsigned short* WtCo = U + u; u += (size_t)6*DD*DD;
  unsigned short* WtF1 = U + u; u += (size_t)6*DD*FFND;
  unsigned short* WtF2 = U + u; u += (size_t)6*DD*FFND;
  unsigned short* WtQB = U + u; u += (size_t)2*DM*DM;       // fused qs1|bbox1 [512][256]
  unsigned short* WtQ2 = U + u; u += (size_t)DM*DM;
  unsigned short* QKb  = PQb;   // fused SA QK output: 16 slots/batch x QLEN rows
  unsigned short* AOb  = QIN;
  unsigned short* HIDb = PKb;
  if (ws_size < o*sizeof(float) + u*sizeof(unsigned short)) return;

  dim3 B256(256);
  const int nTotal = NQROWS*DD;
  const size_t ZD = (size_t)DD*DD;
  const size_t ZM = (size_t)DM*DM;
  const float QSC = 0.125f * LOG2E;

  // ---------- weight transpose+cvt (Wq halves pre-scaled by 0.125*log2e) ----------
  transpose_cvt<<<dim3(16,16,6), B256, 0, stream>>>(sa_Wq, WtSqk,      DD, DD, ZD, 2*ZD, QSC);
  transpose_cvt<<<dim3(16,16,6), B256, 0, stream>>>(sa_Wk, WtSqk + ZD, DD, DD, ZD, 2*ZD, 1.f);
  transpose_cvt<<<dim3(16,16,6), B256, 0, stream>>>(sa_Wv, WtSv, DD, DD, ZD, ZD, 1.f);
  transpose_cvt<<<dim3(16,16,6), B256, 0, stream>>>(sa_Wo, WtSo, DD, DD, ZD, ZD, 1.f);
  transpose_cvt<<<dim3(16,16,6), B256, 0, stream>>>(ca_Wq, WtCq, DD, DD, ZD, ZD, QSC);
  transpose_cvt<<<dim3(16,16,6), B256, 0, stream>>>(ca_Wk, WtCk, DD, DD, ZD, ZD, 1.f);
  transpose_cvt<<<dim3(16,16,6), B256, 0, stream>>>(ca_Wv, WtCv, DD, DD, ZD, ZD, 1.f);
  transpose_cvt<<<dim3(16,16,6), B256, 0, stream>>>(ca_Wo, WtCo, DD, DD, ZD, ZD, 1.f);
  transpose_cvt<<<dim3(32,16,6), B256, 0, stream>>>(ff_W1, WtF1, DD, FFND, (size_t)DD*FFND, (size_t)DD*FFND, 1.f);
  transpose_cvt<<<dim3(16,32,6), B256, 0, stream>>>(ff_W2, WtF2, FFND, DD, (size_t)DD*FFND, (size_t)DD*FFND, 1.f);
  transpose_cvt<<<dim3(8,8,1),  B256, 0, stream>>>(qs_W1, WtQB,      DM, DM, ZM, ZM, 1.f);
  transpose_cvt<<<dim3(8,8,1),  B256, 0, stream>>>(bb_W1, WtQB + ZM, DM, DM, ZM, ZM, 1.f);
  transpose_cvt<<<dim3(8,8,1),  B256, 0, stream>>>(qs_W2, WtQ2, DM, DM, ZM, ZM, 1.f);
  concat_bias<<<dim3(2), B256, 0, stream>>>(qs_b1, bb_b1, QBB);

  // ---------- pre-loop ----------
  init_x<<<dim3((nTotal+255)/256), B256, 0, stream>>>(tgt, query_pos, X, Xb, QIN, nTotal);
  cvt_mem<<<dim3(NMROWS*DD/8/256), B256, 0, stream>>>(memory, pos, MEMb, MEMVb);
  gemm_f32<<<dim3(DM/64, NQROWS/64), B256, 0, stream>>>(query_pos, nullptr, rp_W1, rp_b1, T256, NQROWS, DM, DM, DM, 1);
  gemm_skinny<<<dim3(NQROWS/4), B256, 0, stream>>>(T256, rp_W2, rp_b2, REFB, NQROWS, 2, DM, DM);
  sine_embed_kernel<<<dim3((NQROWS*DM+255)/256), B256, 0, stream>>>(REFB, SINE);

  const int nredu = (128*QLEN + 3) / 4;
  const int qtiles = (QLEN + 63) / 64;
  for (int l = 0; l < 6; ++l) {
    const size_t wo = (size_t)l*DD*DD, fo = (size_t)l*DD*FFND;
    const float* fb1 = ff_b1 + (size_t)l*FFND;
    const float* fb2 = ff_b2 + (size_t)l*DD;

    // fused qs1 (bf16 out) + bbox1 (f32 out), both ReLU, input Xb[:,256:]
    gemm_mfma_split<<<dim3(8, NQROWS/64), B256, 0, stream>>>(Xb+DM, WtQB, QBB, T256b, T256, NQROWS, 512, DM, DD);
    gemm2<32,0,false><<<dim3(DM/128, NQROWS/32), B256, 0, stream>>>(T256b, WtQ2, qs_b2, PT, NQROWS, DM, DM, DM, 0);
    gemm_skinny_boxes<<<dim3(NQROWS/4), B256, 0, stream>>>(T256, bb_W2, bb_b2, REFB, BOX, CS, NQROWS, DM, DM);
    bias_kernel<<<dim3((BATCH*QLEN*QLEN+255)/256), B256, 0, stream>>>(BOX, CS, BIAS);

    // ---- self-attention (QIN written by init_x / previous ln3); NS=1 direct out ----
    gemm2<64,2,false><<<dim3(1024/128, NQROWS/64), B256, 0, stream>>>(QIN, WtSqk + (size_t)l*2*ZD, nullptr, QKb, NQROWS, 1024, DD, DD, QLEN);
    gemm2_vt<64><<<dim3(DD/128, BATCH*5), B256, 0, stream>>>(Xb, WtSv+wo, VTsa, QLEN, DD, DD, SAKPAD, 5);
    attn2<true,true,1><<<dim3(128, qtiles, 1), B256, 0, stream>>>(QKb, QKb, VTsa, BIAS, AOb, OPARTU, ML, QLEN, QLEN, SAKPAD, 16, 16, 8);
    gemm2<32,0,false><<<dim3(DD/128, NQROWS/32), B256, 0, stream>>>(AOb, WtSo+wo, nullptr, RES, NQROWS, DD, DD, DD, 0);
    ln_residual_t<2><<<dim3(NQROWS), B256, 0, stream>>>(X, RES, Xb, query_pos, SINE, PT, QIN);

    // ---- cross-attention (QIN written by ln1 above) ----
    gemm2<32,2,false><<<dim3(DD/128, NQROWS/32), B256, 0, stream>>>(QIN, WtCq+wo, nullptr, PQb, NQROWS, DD, DD, DD, QLEN);
    gemm2<128,2,false><<<dim3(DD/128, NMROWS/128), B256, 0, stream>>>(MEMb,  WtCk+wo, nullptr, PKb, NMROWS, DD, DD, DD, SLEN);
    gemm2_vt<128><<<dim3(DD/128, BATCH*8), B256, 0, stream>>>(MEMVb, WtCv+wo, PVb, SLEN, DD, DD, SLEN, 8);
    attn2<false,false,2><<<dim3(128, qtiles, 2), B256, 0, stream>>>(PQb, PKb, PVb, nullptr, nullptr, OPARTU, ML, QLEN, SLEN, SLEN, 8, 8, 0);
    attn_reduce<2><<<dim3(nredu), B256, 0, stream>>>(OPARTU, ML, AOb, QLEN);
    gemm2<32,0,false><<<dim3(DD/128, NQROWS/32), B256, 0, stream>>>(AOb, WtCo+wo, nullptr, RES, NQROWS, DD, DD, DD, 0);
    ln_residual_t<0><<<dim3(NQROWS), B256, 0, stream>>>(X, RES, Xb, nullptr, nullptr, nullptr, nullptr);

    // ---- FFN ----
    gemm2<64,1,true ><<<dim3(FFND/128, NQROWS/64), B256, 0, stream>>>(Xb, WtF1+fo, fb1, HIDb, NQROWS, FFND, DD, DD, 0);
    gemm2<32,0,false><<<dim3(DD/128, NQROWS/32), B256, 0, stream>>>(HIDb, WtF2+fo, fb2, RES, NQROWS, DD, FFND, FFND, 0);
    ln_residual_t<1><<<dim3(NQROWS), B256, 0, stream>>>(X, RES, Xb, query_pos, nullptr, nullptr, QIN);
  }

  copy_f32<<<dim3((nTotal+255)/256), B256, 0, stream>>>(X, (float*)d_out, out_size);
}

// Round 13
// 1478.268 us; speedup vs baseline: 1.0901x; 1.0217x over previous
//
#include <hip/hip_runtime.h>
#include <cmath>

#define QLEN 300
#define BATCH 16
#define SLEN 1024
#define DM 256
#define DD 512
#define FFND 1024
#define NQROWS (QLEN*BATCH)   // 4800
#define NMROWS (SLEN*BATCH)   // 16384
#define LQPAD 304
#define SAKPAD 320
#define LOG2E 1.4426950408889634f

typedef __attribute__((ext_vector_type(8))) short short8;
typedef __attribute__((ext_vector_type(4))) float f32x4;
typedef __attribute__((ext_vector_type(4))) unsigned short ushort4_;

__device__ __forceinline__ float sigmoidf_(float x){ return 1.f/(1.f+expf(-x)); }

__device__ __forceinline__ unsigned short f2bf(float x){
  unsigned u = __float_as_uint(x);
  unsigned r = (u + 0x7FFFu + ((u >> 16) & 1u)) >> 16;
  return (unsigned short)r;
}
__device__ __forceinline__ float bf2f(unsigned short u){
  return __uint_as_float(((unsigned)u) << 16);
}
// raw v_exp_f32 (2^x) — exp2f() goes through precise OCML, this does not
__device__ __forceinline__ float fexp2(float x){ return __builtin_amdgcn_exp2f(x); }

// async global->LDS, 16B per lane; dest = wave-uniform base + lane*16
__device__ __forceinline__ void gload16(const void* g, void* l) {
  __builtin_amdgcn_global_load_lds((const __attribute__((address_space(1))) unsigned int*)g,
                                   (__attribute__((address_space(3))) unsigned int*)l, 16, 0, 0);
}

// ========== weight transpose + f32->bf16 (+scale) : W[K,N] -> Wt[N,K] ==========
__global__ __launch_bounds__(256) void transpose_cvt(
    const float* __restrict__ W, unsigned short* __restrict__ Wt, int K, int N,
    size_t zsrc, size_t zdst, float scale)
{
  __shared__ float T[32][33];
  int n0 = blockIdx.x*32, k0 = blockIdx.y*32;
  size_t zs = (size_t)blockIdx.z * zsrc;
  size_t zd = (size_t)blockIdx.z * zdst;
  int tx = threadIdx.x & 31, ty = threadIdx.x >> 5;
  #pragma unroll
  for (int j = 0; j < 32; j += 8)
    T[ty+j][tx] = W[zs + (size_t)(k0+ty+j)*N + n0+tx];
  __syncthreads();
  #pragma unroll
  for (int j = 0; j < 32; j += 8)
    Wt[zd + (size_t)(n0+ty+j)*K + k0+tx] = f2bf(T[tx][ty+j] * scale);
}

__global__ void concat_bias(const float* __restrict__ b1, const float* __restrict__ b2,
                            float* __restrict__ out)
{
  int i = blockIdx.x*256 + threadIdx.x;
  if (i < 256) out[i] = b1[i];
  else if (i < 512) out[i] = b2[i-256];
}

// ================= gemm2: pipelined bf16 MFMA GEMM, BN=128, BK=64 =================
// C = act(A @ Wt^T + bias). A bf16 [M,lda]; Wt bf16 [N,K].
// OUTMODE 0: f32 [M,N]; 1: bf16 [M,N];
// OUTMODE 2: bf16 head rows [(b*(N/64)+h)*Laux + q][64]  (rowg = q*16+b)
template<int BM, int OUTMODE, bool RELU>
__global__ __launch_bounds__(256) void gemm2(
    const unsigned short* __restrict__ Ab, const unsigned short* __restrict__ Wt,
    const float* __restrict__ bias, void* __restrict__ Cptr,
    int M, int N, int K, int lda, int Laux)
{
  __shared__ __align__(16) unsigned short As[2][BM*64];
  __shared__ __align__(16) unsigned short Bs[2][128*64];
  const int tid = threadIdx.x;
  const int w = tid >> 6, lane = tid & 63;
  const int bm = blockIdx.y*BM, bn = blockIdx.x*128;
  const int wm = w >> 1, wn = w & 1;
  const int c = lane & 15, hi = lane >> 4;
  constexpr int MR = (BM + 31)/32 < 1 ? 1 : BM/32;
  f32x4 acc[MR < 1 ? 1 : MR][4] = {};
  const int lrow8 = lane >> 3;
  const int lcol  = ((lane & 7) ^ lrow8) << 3;
  const int nt = K >> 6;

  auto stage = [&](int buf, int k0) {
    #pragma unroll
    for (int it = 0; it < BM/32; ++it) {
      int r = it*32 + w*8;
      gload16(&Ab[(size_t)(bm + r + lrow8)*lda + k0 + lcol], &As[buf][r*64]);
    }
    #pragma unroll
    for (int it = 0; it < 4; ++it) {
      int r = it*32 + w*8;
      gload16(&Wt[(size_t)(bn + r + lrow8)*K + k0 + lcol], &Bs[buf][r*64]);
    }
  };

  stage(0, 0);
  for (int t = 0; t < nt; ++t) {
    const int cur = t & 1;
    if (t + 1 < nt) {
      stage(cur ^ 1, (t+1) << 6);
      if constexpr (BM == 32)      asm volatile("s_waitcnt vmcnt(5)" ::: "memory");
      else if constexpr (BM == 64) asm volatile("s_waitcnt vmcnt(6)" ::: "memory");
      else                         asm volatile("s_waitcnt vmcnt(8)" ::: "memory");
    } else {
      asm volatile("s_waitcnt vmcnt(0)" ::: "memory");
    }
    __builtin_amdgcn_s_barrier();
    #pragma unroll
    for (int ks = 0; ks < 2; ++ks) {
      short8 a[MR], bf[4];
      #pragma unroll
      for (int mr = 0; mr < MR; ++mr) {
        int m = wm*(BM/2) + mr*16 + c;
        a[mr] = *reinterpret_cast<const short8*>(&As[cur][m*64 + ((ks*32 + hi*8) ^ ((m&7)<<3))]);
      }
      #pragma unroll
      for (int nr = 0; nr < 4; ++nr) {
        int n = wn*64 + nr*16 + c;
        bf[nr] = *reinterpret_cast<const short8*>(&Bs[cur][n*64 + ((ks*32 + hi*8) ^ ((n&7)<<3))]);
      }
      #pragma unroll
      for (int mr = 0; mr < MR; ++mr)
        #pragma unroll
        for (int nr = 0; nr < 4; ++nr)
          acc[mr][nr] = __builtin_amdgcn_mfma_f32_16x16x32_bf16(a[mr], bf[nr], acc[mr][nr], 0, 0, 0);
    }
    asm volatile("s_waitcnt lgkmcnt(0)" ::: "memory");
    __builtin_amdgcn_sched_barrier(0);
    __builtin_amdgcn_s_barrier();
  }
  const int hs = N >> 6;
  #pragma unroll
  for (int mr = 0; mr < MR; ++mr) {
    #pragma unroll
    for (int nr = 0; nr < 4; ++nr) {
      int colg = bn + wn*64 + nr*16 + c;
      float bv = bias ? bias[colg] : 0.f;
      #pragma unroll
      for (int r = 0; r < 4; ++r) {
        int rowg = bm + wm*(BM/2) + mr*16 + hi*4 + r;
        float v = acc[mr][nr][r] + bv;
        if (RELU) v = fmaxf(v, 0.f);
        if (OUTMODE == 0) {
          ((float*)Cptr)[(size_t)rowg*N + colg] = v;
        } else if (OUTMODE == 1) {
          ((unsigned short*)Cptr)[(size_t)rowg*N + colg] = f2bf(v);
        } else {
          int bb = rowg & 15, row = rowg >> 4, h = colg >> 6, dl = colg & 63;
          ((unsigned short*)Cptr)[(((size_t)bb*hs + h)*Laux + row)*64 + dl] = f2bf(v);
        }
      }
    }
  }
}

// ================= gemm2_vt: V-projection producing V^T, per-batch tiles ==========
template<int BM>
__global__ __launch_bounds__(256) void gemm2_vt(
    const unsigned short* __restrict__ Ab, const unsigned short* __restrict__ Wt,
    unsigned short* __restrict__ VT, int Lsrc, int K, int lda, int Lkpad, int tilesPerB)
{
  __shared__ __align__(16) unsigned short As[2][BM*64];
  __shared__ __align__(16) unsigned short Bs[2][128*64];
  const int tid = threadIdx.x;
  const int w = tid >> 6, lane = tid & 63;
  const int b = blockIdx.y / tilesPerB;
  const int qt = (blockIdx.y - b*tilesPerB) * BM;
  const int bn = blockIdx.x*128;
  const int wm = w >> 1, wn = w & 1;
  const int c = lane & 15, hi = lane >> 4;
  constexpr int MR = BM/32;
  f32x4 acc[MR][4] = {};
  const int lrow8 = lane >> 3;
  const int lcol  = ((lane & 7) ^ lrow8) << 3;
  const int nt = K >> 6;

  auto stage = [&](int buf, int k0) {
    #pragma unroll
    for (int it = 0; it < BM/32; ++it) {
      int r = it*32 + w*8;
      int q = qt + r + lrow8; if (q > Lsrc-1) q = Lsrc-1;
      gload16(&Ab[(size_t)(q*BATCH + b)*lda + k0 + lcol], &As[buf][r*64]);
    }
    #pragma unroll
    for (int it = 0; it < 4; ++it) {
      int r = it*32 + w*8;
      gload16(&Wt[(size_t)(bn + r + lrow8)*K + k0 + lcol], &Bs[buf][r*64]);
    }
  };

  stage(0, 0);
  for (int t = 0; t < nt; ++t) {
    const int cur = t & 1;
    if (t + 1 < nt) {
      stage(cur ^ 1, (t+1) << 6);
      if constexpr (BM == 64) asm volatile("s_waitcnt vmcnt(6)" ::: "memory");
      else                    asm volatile("s_waitcnt vmcnt(8)" ::: "memory");
    } else {
      asm volatile("s_waitcnt vmcnt(0)" ::: "memory");
    }
    __builtin_amdgcn_s_barrier();
    #pragma unroll
    for (int ks = 0; ks < 2; ++ks) {
      short8 a[MR], bf[4];
      #pragma unroll
      for (int mr = 0; mr < MR; ++mr) {
        int m = wm*(BM/2) + mr*16 + c;
        a[mr] = *reinterpret_cast<const short8*>(&As[cur][m*64 + ((ks*32 + hi*8) ^ ((m&7)<<3))]);
      }
      #pragma unroll
      for (int nr = 0; nr < 4; ++nr) {
        int n = wn*64 + nr*16 + c;
        bf[nr] = *reinterpret_cast<const short8*>(&Bs[cur][n*64 + ((ks*32 + hi*8) ^ ((n&7)<<3))]);
      }
      #pragma unroll
      for (int mr = 0; mr < MR; ++mr)
        #pragma unroll
        for (int nr = 0; nr < 4; ++nr)
          acc[mr][nr] = __builtin_amdgcn_mfma_f32_16x16x32_bf16(a[mr], bf[nr], acc[mr][nr], 0, 0, 0);
    }
    asm volatile("s_waitcnt lgkmcnt(0)" ::: "memory");
    __builtin_amdgcn_sched_barrier(0);
    __builtin_amdgcn_s_barrier();
  }
  #pragma unroll
  for (int mr = 0; mr < MR; ++mr) {
    #pragma unroll
    for (int nr = 0; nr < 4; ++nr) {
      int colg = bn + wn*64 + nr*16 + c;
      int h = colg >> 6, dl = colg & 63;
      int q0 = qt + wm*(BM/2) + mr*16 + hi*4;
      ushort4_ pack;
      #pragma unroll
      for (int r = 0; r < 4; ++r) pack[r] = f2bf(acc[mr][nr][r]);
      *reinterpret_cast<ushort4_*>(&VT[((size_t)(b*8 + h)*64 + dl)*Lkpad + q0]) = pack;
    }
  }
}

// ===== fused qs1+bbox1: A bf16 [M,lda]; N=512 (cols 0..255 -> bf16 C1, 256..511 -> f32 C2), ReLU =====
__global__ __launch_bounds__(256) void gemm_mfma_split(
    const unsigned short* __restrict__ Ab, const unsigned short* __restrict__ Wt,
    const float* __restrict__ bias, unsigned short* __restrict__ C1, float* __restrict__ C2,
    int M, int N, int K, int lda)
{
  __shared__ __align__(16) unsigned short As[64][72];
  __shared__ __align__(16) unsigned short Bs[64][72];
  const int tid = threadIdx.x;
  const int bm = blockIdx.y*64, bn = blockIdx.x*64;
  const int w = tid >> 6, lane = tid & 63;
  const int wm = w >> 1, wn = w & 1;
  const int c = lane & 15, hi = lane >> 4;
  const int sr = tid >> 3, sk = (tid & 7) * 8;
  f32x4 acc[2][2] = {};
  for (int k0 = 0; k0 < K; k0 += 64) {
    #pragma unroll
    for (int it = 0; it < 2; ++it) {
      int m = sr + it*32;
      short8 v = *reinterpret_cast<const short8*>(&Ab[(size_t)(bm+m)*lda + k0 + sk]);
      *reinterpret_cast<short8*>(&As[m][sk]) = v;
      short8 bv = *reinterpret_cast<const short8*>(&Wt[(size_t)(bn+m)*K + k0 + sk]);
      *reinterpret_cast<short8*>(&Bs[m][sk]) = bv;
    }
    __syncthreads();
    #pragma unroll
    for (int ks = 0; ks < 2; ++ks) {
      short8 a0 = *reinterpret_cast<const short8*>(&As[wm*32 + c][ks*32 + hi*8]);
      short8 a1 = *reinterpret_cast<const short8*>(&As[wm*32 + 16 + c][ks*32 + hi*8]);
      short8 b0 = *reinterpret_cast<const short8*>(&Bs[wn*32 + c][ks*32 + hi*8]);
      short8 b1 = *reinterpret_cast<const short8*>(&Bs[wn*32 + 16 + c][ks*32 + hi*8]);
      acc[0][0] = __builtin_amdgcn_mfma_f32_16x16x32_bf16(a0, b0, acc[0][0], 0, 0, 0);
      acc[0][1] = __builtin_amdgcn_mfma_f32_16x16x32_bf16(a0, b1, acc[0][1], 0, 0, 0);
      acc[1][0] = __builtin_amdgcn_mfma_f32_16x16x32_bf16(a1, b0, acc[1][0], 0, 0, 0);
      acc[1][1] = __builtin_amdgcn_mfma_f32_16x16x32_bf16(a1, b1, acc[1][1], 0, 0, 0);
    }
    __syncthreads();
  }
  #pragma unroll
  for (int mf = 0; mf < 2; ++mf) {
    #pragma unroll
    for (int nf = 0; nf < 2; ++nf) {
      int colg = bn + wn*32 + nf*16 + c;
      float bv = bias[colg];
      #pragma unroll
      for (int r = 0; r < 4; ++r) {
        int rowg = bm + wm*32 + mf*16 + hi*4 + r;
        float v = fmaxf(acc[mf][nf][r] + bv, 0.f);
        if (colg < 256) C1[(size_t)rowg*256 + colg] = f2bf(v);
        else            C2[(size_t)rowg*256 + (colg-256)] = v;
      }
    }
  }
}

// ================= attn2: pipelined MFMA flash attention (swapped QK^T, exp2 units) ==
// Q rows at (b*qmul + h)*Lq (Wq pre-scaled by 0.125*log2e); K rows at (b*kmul+koff+h)*Lk;
// bias pre-scaled by log2e. VT [(b*8+h)*64+d][Lkpad]. Defer-rescale THR=8*log2e.
// Pl swizzled (no pad): 16B chunk ^= (c&7); LDS = 40960 B.
template<bool HAS_BIAS, bool MASK, int NS>
__global__ __launch_bounds__(256) void attn2(
    const unsigned short* __restrict__ Qh, const unsigned short* __restrict__ Kh,
    const unsigned short* __restrict__ VT, const float* __restrict__ bias,
    unsigned short* __restrict__ Ob, unsigned short* __restrict__ Opart, float* __restrict__ MLpart,
    int Lq, int Lk, int Lkpad, int qmul, int kmul, int koff)
{
  __shared__ __align__(16) unsigned short Ks[2][64*64];
  __shared__ __align__(16) unsigned short Vs[2][64*64];
  __shared__ __align__(16) unsigned short Pl[4][16*64];
  const int tid = threadIdx.x;
  const int w = tid >> 6, lane = tid & 63;
  const int c = lane & 15, hi = lane >> 4;
  const int bh = blockIdx.x;
  const int qt = blockIdx.y * 64;
  const int sp = blockIdx.z;
  const int b = bh >> 3, h = bh & 7;
  const int lrow8 = lane >> 3;
  const int lcol  = ((lane & 7) ^ lrow8) << 3;

  const int nt_tot = (Lk + 63) >> 6;
  const int t0 = (nt_tot * sp) / NS;
  const int t1 = (nt_tot * (sp + 1)) / NS;

  int qrow = qt + w*16 + c; if (qrow > Lq-1) qrow = Lq-1;
  const unsigned short* qptr = Qh + ((size_t)(b*qmul + h)*Lq + qrow)*64;
  short8 qf0 = *reinterpret_cast<const short8*>(qptr + hi*8);
  short8 qf1 = *reinterpret_cast<const short8*>(qptr + 32 + hi*8);
  const size_t kbase = (size_t)(b*kmul + koff + h)*Lk;

  float m_ = -1e30f, l_ = 0.f;
  f32x4 accO[4] = {};
  const int qbase = qt + w*16 + hi*4;

  auto stageKV = [&](int buf, int kt) {
    #pragma unroll
    for (int it = 0; it < 2; ++it) {
      int r = it*32 + w*8;
      int kr = kt + r + lrow8; if (MASK && kr > Lk-1) kr = Lk-1;
      gload16(&Kh[(kbase + kr)*64 + lcol], &Ks[buf][r*64]);
    }
    #pragma unroll
    for (int it = 0; it < 2; ++it) {
      int r = it*32 + w*8;
      gload16(&VT[((size_t)bh*64 + r + lrow8)*Lkpad + kt + lcol], &Vs[buf][r*64]);
    }
  };

  stageKV(0, t0 << 6);
  for (int t = t0; t < t1; ++t) {
    const int cur = (t - t0) & 1;
    const int kt = t << 6;
    float4 bs4[4];
    if (HAS_BIAS) {
      #pragma unroll
      for (int g = 0; g < 4; ++g)
        bs4[g] = *reinterpret_cast<const float4*>(
            &bias[((size_t)b*Lq + qrow)*Lk + kt + g*16 + hi*4]);
    }
    if (t + 1 < t1) {
      stageKV(cur ^ 1, (t+1) << 6);
      asm volatile("s_waitcnt vmcnt(4)" ::: "memory");
    } else {
      asm volatile("s_waitcnt vmcnt(0)" ::: "memory");
    }
    __builtin_amdgcn_s_barrier();
    // ---- S^T = K Q^T  (log2e & 1/8 folded into Q projection) ----
    f32x4 s[4] = {};
    __builtin_amdgcn_s_setprio(1);
    #pragma unroll
    for (int g = 0; g < 4; ++g) {
      int m = g*16 + c;
      short8 kb0 = *reinterpret_cast<const short8*>(&Ks[cur][m*64 + ((hi*8)      ^ ((m&7)<<3))]);
      short8 kb1 = *reinterpret_cast<const short8*>(&Ks[cur][m*64 + ((32 + hi*8) ^ ((m&7)<<3))]);
      s[g] = __builtin_amdgcn_mfma_f32_16x16x32_bf16(kb0, qf0, s[g], 0, 0, 0);
      s[g] = __builtin_amdgcn_mfma_f32_16x16x32_bf16(kb1, qf1, s[g], 0, 0, 0);
    }
    __builtin_amdgcn_s_setprio(0);
    // ---- logits + lane-local online softmax (base-2) ----
    float tmax = -1e30f;
    #pragma unroll
    for (int g = 0; g < 4; ++g) {
      #pragma unroll
      for (int r = 0; r < 4; ++r) {
        float v = s[g][r];
        if (HAS_BIAS) v += ((const float*)&bs4[g])[r];
        if (MASK && (kt + g*16 + hi*4 + r >= Lk)) v = -1e30f;
        s[g][r] = v;
        tmax = fmaxf(tmax, v);
      }
    }
    tmax = fmaxf(tmax, __shfl_xor(tmax, 16));
    tmax = fmaxf(tmax, __shfl_xor(tmax, 32));
    // T13 defer-rescale: skip when growth <= 8*log2e (P bounded by 2^11.54)
    if (!__all(tmax - m_ <= 11.5416f)) {
      float newm = fmaxf(m_, tmax);
      float corr = fexp2(m_ - newm);
      m_ = newm;
      l_ *= corr;
      float corr4[4];
      #pragma unroll
      for (int r = 0; r < 4; ++r) corr4[r] = __shfl(corr, hi*4 + r);
      #pragma unroll
      for (int dg = 0; dg < 4; ++dg)
        #pragma unroll
        for (int r = 0; r < 4; ++r) accO[dg][r] *= corr4[r];
    }
    float psum = 0.f;
    #pragma unroll
    for (int g = 0; g < 4; ++g) {
      ushort4_ pp;
      #pragma unroll
      for (int r = 0; r < 4; ++r) {
        float e = fexp2(s[g][r] - m_);
        psum += e;
        pp[r] = f2bf(e);
      }
      // write P[q=c][keys g*16+hi*4..+3]: chunk (2g|(hi>>1)) ^ (c&7), half (hi&1)
      int idx = c*64 + ((((g<<1)|(hi>>1)) ^ (c&7))<<3) + ((hi&1)<<2);
      *reinterpret_cast<ushort4_*>(&Pl[w][idx]) = pp;
    }
    psum += __shfl_xor(psum, 16);
    psum += __shfl_xor(psum, 32);
    l_ += psum;
    // ---- O += P V ----
    __builtin_amdgcn_s_setprio(1);
    #pragma unroll
    for (int ks = 0; ks < 2; ++ks) {
      // read P[q=c][keys ks*32+hi*8..+7]: chunk (ks*4+hi) ^ (c&7)
      short8 pa = *reinterpret_cast<const short8*>(&Pl[w][c*64 + ((((ks<<2)|hi) ^ (c&7))<<3)]);
      #pragma unroll
      for (int dg = 0; dg < 4; ++dg) {
        int n = dg*16 + c;
        short8 vb = *reinterpret_cast<const short8*>(&Vs[cur][n*64 + ((ks*32 + hi*8) ^ ((n&7)<<3))]);
        accO[dg] = __builtin_amdgcn_mfma_f32_16x16x32_bf16(pa, vb, accO[dg], 0, 0, 0);
      }
    }
    __builtin_amdgcn_s_setprio(0);
    asm volatile("s_waitcnt lgkmcnt(0)" ::: "memory");
    __builtin_amdgcn_sched_barrier(0);
    __builtin_amdgcn_s_barrier();
  }
  // ---- epilogue ----
  if (NS == 1) {
    float l4[4];
    #pragma unroll
    for (int r = 0; r < 4; ++r) l4[r] = __shfl(l_, hi*4 + r);
    #pragma unroll
    for (int r = 0; r < 4; ++r) {
      int qg = qbase + r;
      if (qg < Lq) {
        float inv = 1.f / l4[r];
        #pragma unroll
        for (int dg = 0; dg < 4; ++dg)
          Ob[((size_t)qg*BATCH + b)*DD + h*64 + 16*dg + c] = f2bf(accO[dg][r] * inv);
      }
    }
  } else {
    int qc = qt + w*16 + c;
    if (hi == 0 && qc < Lq) {
      size_t rowml = ((size_t)sp*128 + bh)*LQPAD + qc;
      MLpart[rowml*2]     = m_;
      MLpart[rowml*2 + 1] = l_;
    }
    #pragma unroll
    for (int r = 0; r < 4; ++r) {
      int qg = qbase + r;
      if (qg < Lq) {
        size_t rowo = ((size_t)sp*128 + bh)*LQPAD + qg;
        #pragma unroll
        for (int dg = 0; dg < 4; ++dg)
          Opart[rowo*64 + dg*16 + c] = f2bf(accO[dg][r]);
      }
    }
  }
}

// combine NSR partials (m in log2 units) -> bf16 out [q*16+b][512]
template<int NSR>
__global__ __launch_bounds__(256) void attn_reduce(
    const unsigned short* __restrict__ Opart, const float* __restrict__ MLpart,
    unsigned short* __restrict__ Ob, int Lq)
{
  int w = threadIdx.x >> 6, lane = threadIdx.x & 63;
  int pair = blockIdx.x*4 + w;
  if (pair >= 128*Lq) return;
  int bh = pair / Lq, q = pair - bh*Lq;
  size_t rr[NSR];
  float m[NSR], l[NSR], M = -1e30f;
  #pragma unroll
  for (int s = 0; s < NSR; ++s) {
    rr[s] = ((size_t)s*128 + bh)*LQPAD + q;
    m[s] = MLpart[rr[s]*2];
    l[s] = MLpart[rr[s]*2 + 1];
    M = fmaxf(M, m[s]);
  }
  float o = 0.f, L = 0.f;
  #pragma unroll
  for (int s = 0; s < NSR; ++s) {
    float wg = fexp2(m[s] - M);
    o += wg * bf2f(Opart[rr[s]*64 + lane]);
    L += wg * l[s];
  }
  int b = bh >> 3, h = bh & 7;
  Ob[((size_t)q*BATCH + b)*DD + h*64 + lane] = f2bf(o / L);
}

// ================= f32 GEMM (pre-loop rp MLP only) =================
__global__ __launch_bounds__(256) void gemm_f32(
    const float* __restrict__ A, const float* __restrict__ A2,
    const float* __restrict__ W, const float* __restrict__ bias,
    float* __restrict__ C, int M, int N, int K, int lda, int relu)
{
  __shared__ __align__(16) float As[16][68];
  __shared__ __align__(16) float Bs[16][68];
  const int tid = threadIdx.x;
  const int bm = blockIdx.y * 64, bn = blockIdx.x * 64;
  const int tx = tid & 15, ty = tid >> 4;
  const int ar = tid >> 4, ac = tid & 15;
  const int bk = tid >> 6, bnn = tid & 63;
  float acc[4][4] = {};
  for (int k0 = 0; k0 < K; k0 += 16) {
    #pragma unroll
    for (int i = 0; i < 4; ++i) {
      int row = ar + i*16;
      float v = A[(size_t)(bm+row)*lda + (k0+ac)];
      if (A2) v += A2[(size_t)(bm+row)*lda + (k0+ac)];
      As[ac][row] = v;
    }
    #pragma unroll
    for (int i = 0; i < 4; ++i) {
      int kk = bk + i*4;
      Bs[kk][bnn] = W[(size_t)(k0+kk)*N + (bn+bnn)];
    }
    __syncthreads();
    #pragma unroll
    for (int k = 0; k < 16; ++k) {
      float4 a4 = *reinterpret_cast<const float4*>(&As[k][ty*4]);
      float4 b4 = *reinterpret_cast<const float4*>(&Bs[k][tx*4]);
      float a[4] = {a4.x,a4.y,a4.z,a4.w};
      float bb[4] = {b4.x,b4.y,b4.z,b4.w};
      #pragma unroll
      for (int i=0;i<4;++i)
        #pragma unroll
        for (int j=0;j<4;++j)
          acc[i][j] = fmaf(a[i], bb[j], acc[i][j]);
    }
    __syncthreads();
  }
  float vb[4] = {0.f,0.f,0.f,0.f};
  if (bias) {
    float4 b4 = *reinterpret_cast<const float4*>(&bias[bn + tx*4]);
    vb[0]=b4.x; vb[1]=b4.y; vb[2]=b4.z; vb[3]=b4.w;
  }
  #pragma unroll
  for (int i=0;i<4;++i) {
    int row = bm + ty*4 + i;
    float r0 = acc[i][0]+vb[0], r1 = acc[i][1]+vb[1], r2 = acc[i][2]+vb[2], r3 = acc[i][3]+vb[3];
    if (relu){ r0=fmaxf(r0,0.f); r1=fmaxf(r1,0.f); r2=fmaxf(r2,0.f); r3=fmaxf(r3,0.f); }
    float4 o; o.x=r0; o.y=r1; o.z=r2; o.w=r3;
    *reinterpret_cast<float4*>(&C[(size_t)row*N + bn + tx*4]) = o;
  }
}

// rp MLP final layer (N=2): plain skinny
__global__ __launch_bounds__(256) void gemm_skinny(
    const float* __restrict__ A, const float* __restrict__ W, const float* __restrict__ bias,
    float* __restrict__ C, int M, int N, int K, int lda)
{
  int wid = threadIdx.x >> 6, lane = threadIdx.x & 63;
  int row = blockIdx.x * 4 + wid;
  if (row >= M) return;
  float acc[4] = {0.f,0.f,0.f,0.f};
  for (int k = lane; k < K; k += 64) {
    float av = A[(size_t)row*lda + k];
    for (int n = 0; n < N; ++n) acc[n] += av * W[(size_t)k*N + n];
  }
  for (int off = 32; off; off >>= 1)
    for (int n = 0; n < N; ++n) acc[n] += __shfl_down(acc[n], off);
  if (lane == 0)
    for (int n = 0; n < N; ++n) C[(size_t)row*N + n] = acc[n] + bias[n];
}

// bbox final layer (N=4) fused with boxes/cs epilogue
__global__ __launch_bounds__(256) void gemm_skinny_boxes(
    const float* __restrict__ A, const float* __restrict__ W, const float* __restrict__ bias,
    const float* __restrict__ refb, float* __restrict__ boxes, float* __restrict__ cs,
    int M, int K, int lda)
{
  int wid = threadIdx.x >> 6, lane = threadIdx.x & 63;
  int row = blockIdx.x * 4 + wid;
  if (row >= M) return;
  float acc[4] = {0.f,0.f,0.f,0.f};
  for (int k = lane; k < K; k += 64) {
    float av = A[(size_t)row*lda + k];
    #pragma unroll
    for (int n = 0; n < 4; ++n) acc[n] += av * W[(size_t)k*4 + n];
  }
  for (int off = 32; off; off >>= 1)
    #pragma unroll
    for (int n = 0; n < 4; ++n) acc[n] += __shfl_down(acc[n], off);
  if (lane == 0) {
    int q = row / BATCH, b = row - q*BATCH;
    float cx = sigmoidf_(acc[0] + bias[0] + refb[row*2+0]);
    float cy = sigmoidf_(acc[1] + bias[1] + refb[row*2+1]);
    float w_ = sigmoidf_(acc[2] + bias[2]);
    float h_ = sigmoidf_(acc[3] + bias[3]);
    int o = b*QLEN + q;
    boxes[o*4+0] = cx - 0.5f*w_;
    boxes[o*4+1] = cy - 0.5f*h_;
    boxes[o*4+2] = cx + 0.5f*w_;
    boxes[o*4+3] = cy + 0.5f*h_;
    cs[o] = cx + cy;
  }
}

__global__ void sine_embed_kernel(const float* __restrict__ refb, float* __restrict__ sine)
{
  int idx = blockIdx.x*blockDim.x + threadIdx.x;
  if (idx >= NQROWS*DM) return;
  int r = idx >> 8, c = idx & 255;
  int j = c & 127;
  float coord = refb[r*2 + (c < 128 ? 1 : 0)];
  float s = sigmoidf_(coord);
  float freq = expf(-(float)(j >> 1) * (9.210340371976184f / 64.f));
  float v = s * 6.283185307179586f * freq;
  sine[idx] = (j & 1) ? cosf(v) : sinf(v);
}

// bias[b,i,j] = (IoU + order) * log2e  (exp2-unit softmax downstream)
__global__ void bias_kernel(const float* __restrict__ boxes, const float* __restrict__ cs,
                            float* __restrict__ bias)
{
  int idx = blockIdx.x*blockDim.x + threadIdx.x;
  const int QQ = QLEN*QLEN;
  if (idx >= BATCH*QQ) return;
  int b = idx / QQ, rem = idx - b*QQ;
  int i = rem / QLEN, j = rem - i*QLEN;
  float4 bi = *reinterpret_cast<const float4*>(&boxes[((size_t)b*QLEN + i)*4]);
  float4 bj = *reinterpret_cast<const float4*>(&boxes[((size_t)b*QLEN + j)*4]);
  float ai = (bi.z-bi.x)*(bi.w-bi.y);
  float aj = (bj.z-bj.x)*(bj.w-bj.y);
  float ltx = fmaxf(bi.x, bj.x), lty = fmaxf(bi.y, bj.y);
  float rbx = fminf(bi.z, bj.z), rby = fminf(bi.w, bj.w);
  float w = fmaxf(rbx-ltx, 0.f), h = fmaxf(rby-lty, 0.f);
  float inter = w*h;
  float iou = inter / (ai + aj - inter);
  bias[idx] = (iou + ((cs[b*QLEN+i] > cs[b*QLEN+j]) ? 1.f : 0.f)) * LOG2E;
}

// memory / memory+pos -> bf16, once per call (loop-invariant)
__global__ void cvt_mem(const float* __restrict__ mem, const float* __restrict__ pos,
                        unsigned short* __restrict__ mb, unsigned short* __restrict__ mvb)
{
  int i = blockIdx.x*blockDim.x + threadIdx.x;
  if (i >= NMROWS*DD/8) return;
  size_t base = (size_t)i*8;
  float4 a0 = *reinterpret_cast<const float4*>(mem+base);
  float4 a1 = *reinterpret_cast<const float4*>(mem+base+4);
  float4 p0 = *reinterpret_cast<const float4*>(pos+base);
  float4 p1 = *reinterpret_cast<const float4*>(pos+base+4);
  short8 s1, s2;
  s1[0]=(short)f2bf(a0.x+p0.x); s1[1]=(short)f2bf(a0.y+p0.y); s1[2]=(short)f2bf(a0.z+p0.z); s1[3]=(short)f2bf(a0.w+p0.w);
  s1[4]=(short)f2bf(a1.x+p1.x); s1[5]=(short)f2bf(a1.y+p1.y); s1[6]=(short)f2bf(a1.z+p1.z); s1[7]=(short)f2bf(a1.w+p1.w);
  s2[0]=(short)f2bf(a0.x); s2[1]=(short)f2bf(a0.y); s2[2]=(short)f2bf(a0.z); s2[3]=(short)f2bf(a0.w);
  s2[4]=(short)f2bf(a1.x); s2[5]=(short)f2bf(a1.y); s2[6]=(short)f2bf(a1.z); s2[7]=(short)f2bf(a1.w);
  *reinterpret_cast<short8*>(mb+base)  = s1;
  *reinterpret_cast<short8*>(mvb+base) = s2;
}

// ===== residual + LN, in-place on X, emits bf16 Xb; EMIT 1: QIN=bf16(o+qp2); EMIT 2: QIN=bf16(o+qp2+sine*pt) =====
template<int EMIT>
__global__ __launch_bounds__(256) void ln_residual_t(
    float* __restrict__ X, const float* __restrict__ Y, unsigned short* __restrict__ Xb,
    const float* __restrict__ qp, const float* __restrict__ sine, const float* __restrict__ pt,
    unsigned short* __restrict__ QIN)
{
  int row = blockIdx.x, tid = threadIdx.x;
  size_t base = (size_t)row*DD;
  float v0 = X[base+tid]     + Y[base+tid];
  float v1 = X[base+tid+256] + Y[base+tid+256];
  float s = v0+v1, sq = v0*v0+v1*v1;
  for (int off = 32; off; off >>= 1) { s += __shfl_down(s,off); sq += __shfl_down(sq,off); }
  __shared__ float ss[4], ssq[4];
  int wid = tid>>6, lane = tid&63;
  if (lane==0){ ss[wid]=s; ssq[wid]=sq; }
  __syncthreads();
  if (tid==0){
    float a=ss[0]+ss[1]+ss[2]+ss[3], bsum=ssq[0]+ssq[1]+ssq[2]+ssq[3];
    float mean = a*(1.f/DD);
    float var  = bsum*(1.f/DD) - mean*mean;
    ss[0]=mean; ssq[0]=rsqrtf(fmaxf(var,0.f)+1e-5f);
  }
  __syncthreads();
  float mean = ss[0], inv = ssq[0];
  float o0 = (v0-mean)*inv, o1 = (v1-mean)*inv;
  X[base+tid]     = o0;  Xb[base+tid]     = f2bf(o0);
  X[base+tid+256] = o1;  Xb[base+tid+256] = f2bf(o1);
  if (EMIT >= 1) {
    size_t c2 = (size_t)row*256 + tid;
    float add = qp[c2];
    if (EMIT == 2) add += sine[c2]*pt[c2];
    QIN[base+tid]     = f2bf(o0 + add);
    QIN[base+tid+256] = f2bf(o1 + add);
  }
}

// init: X=tgt, Xb=bf16(tgt), QIN=bf16(tgt+qp2)
__global__ void init_x(const float* __restrict__ t, const float* __restrict__ qp,
                       float* __restrict__ X, unsigned short* __restrict__ Xb,
                       unsigned short* __restrict__ QIN, int n)
{
  int idx = blockIdx.x*blockDim.x + threadIdx.x;
  if (idx < n){
    float v = t[idx]; X[idx]=v; Xb[idx]=f2bf(v);
    int r = idx >> 9, c = idx & 511;
    QIN[idx] = f2bf(v + qp[(r<<8) + (c & 255)]);
  }
}

__global__ void copy_f32(const float* __restrict__ src, float* __restrict__ dst, int n)
{
  int idx = blockIdx.x*blockDim.x + threadIdx.x;
  if (idx < n) dst[idx] = src[idx];
}

extern "C" void kernel_launch(void* const* d_in, const int* in_sizes, int n_in,
                              void* d_out, int out_size, void* d_ws, size_t ws_size,
                              hipStream_t stream)
{
  const float* tgt       = (const float*)d_in[0];
  const float* memory    = (const float*)d_in[1];
  const float* pos       = (const float*)d_in[2];
  const float* query_pos = (const float*)d_in[3];
  const float* qs_W1 = (const float*)d_in[4];  const float* qs_b1 = (const float*)d_in[5];
  const float* qs_W2 = (const float*)d_in[6];  const float* qs_b2 = (const float*)d_in[7];
  const float* rp_W1 = (const float*)d_in[8];  const float* rp_b1 = (const float*)d_in[9];
  const float* rp_W2 = (const float*)d_in[10]; const float* rp_b2 = (const float*)d_in[11];
  const float* bb_W1 = (const float*)d_in[12]; const float* bb_b1 = (const float*)d_in[13];
  const float* bb_W2 = (const float*)d_in[14]; const float* bb_b2 = (const float*)d_in[15];
  const float* sa_Wq = (const float*)d_in[16]; const float* sa_Wk = (const float*)d_in[17];
  const float* sa_Wv = (const float*)d_in[18]; const float* sa_Wo = (const float*)d_in[19];
  const float* ca_Wq = (const float*)d_in[20]; const float* ca_Wk = (const float*)d_in[21];
  const float* ca_Wv = (const float*)d_in[22]; const float* ca_Wo = (const float*)d_in[23];
  const float* ff_W1 = (const float*)d_in[24]; const float* ff_b1 = (const float*)d_in[25];
  const float* ff_W2 = (const float*)d_in[26]; const float* ff_b2 = (const float*)d_in[27];

  // ---------- workspace layout ----------
  float* F = (float*)d_ws;
  size_t o = 0;
  float* X    = F + o; o += (size_t)NQROWS*DD;
  float* RES  = F + o; o += (size_t)NQROWS*DD;
  float* SINE = F + o; o += (size_t)NQROWS*DM;
  float* PT   = F + o; o += (size_t)NQROWS*DM;
  float* BIAS = F + o; o += (size_t)BATCH*QLEN*QLEN;
  float* REFB = F + o; o += (size_t)NQROWS*2;
  float* BOX  = F + o; o += (size_t)NQROWS*4;
  float* CS   = F + o; o += (size_t)NQROWS;
  float* ML   = F + o; o += (size_t)2*128*LQPAD*2;
  float* QBB  = F + o; o += 512;
  float* T256 = RES;   // alias (lifetime-disjoint)
  unsigned short* U = (unsigned short*)(F + o);
  size_t u = 0;
  unsigned short* Xb   = U + u; u += (size_t)NQROWS*DD;
  unsigned short* QIN  = U + u; u += (size_t)NQROWS*DD;
  unsigned short* PQb  = U + u; u += (size_t)NQROWS*DD;     // with PKb: fused SA QK buffer
  unsigned short* PKb  = U + u; u += (size_t)NMROWS*DD;
  unsigned short* PVb  = U + u; u += (size_t)NMROWS*DD;     // CA V^T [128*64][1024]
  unsigned short* VTsa = U + u; u += (size_t)128*64*SAKPAD; // SA V^T [128*64][320]
  unsigned short* OPARTU = U + u; u += (size_t)2*128*LQPAD*64;
  unsigned short* T256b= U + u; u += (size_t)NQROWS*DM;
  unsigned short* MEMb = U + u; u += (size_t)NMROWS*DD;
  unsigned short* MEMVb= U + u; u += (size_t)NMROWS*DD;
  unsigned short* WtSqk= U + u; u += (size_t)6*2*DD*DD;     // fused [1024][512]/layer (Q half pre-scaled)
  unsigned short* WtSv = U + u; u += (size_t)6*DD*DD;
  unsigned short* WtSo = U + u; u += (size_t)6*DD*DD;
  unsigned short* WtCq = U + u; u += (size_t)6*DD*DD;       // pre-scaled by 0.125*log2e
  unsigned short* WtCk = U + u; u += (size_t)6*DD*DD;
  unsigned short* WtCv = U + u; u += (size_t)6*DD*DD;
  unsigned short* WtCo = U + u; u += (size_t)6*DD*DD;
  unsigned short* WtF1 = U + u; u += (size_t)6*DD*FFND;
  unsigned short* WtF2 = U + u; u += (size_t)6*DD*FFND;
  unsigned short* WtQB = U + u; u += (size_t)2*DM*DM;       // fused qs1|bbox1 [512][256]
  unsigned short* WtQ2 = U + u; u += (size_t)DM*DM;
  unsigned short* QKb  = PQb;   // fused SA QK output: 16 slots/batch x QLEN rows
  unsigned short* AOb  = QIN;
  unsigned short* HIDb = PKb;
  if (ws_size < o*sizeof(float) + u*sizeof(unsigned short)) return;

  dim3 B256(256);
  const int nTotal = NQROWS*DD;
  const size_t ZD = (size_t)DD*DD;
  const size_t ZM = (size_t)DM*DM;
  const float QSC = 0.125f * LOG2E;

  // ---------- weight transpose+cvt (Wq halves pre-scaled by 0.125*log2e) ----------
  transpose_cvt<<<dim3(16,16,6), B256, 0, stream>>>(sa_Wq, WtSqk,      DD, DD, ZD, 2*ZD, QSC);
  transpose_cvt<<<dim3(16,16,6), B256, 0, stream>>>(sa_Wk, WtSqk + ZD, DD, DD, ZD, 2*ZD, 1.f);
  transpose_cvt<<<dim3(16,16,6), B256, 0, stream>>>(sa_Wv, WtSv, DD, DD, ZD, ZD, 1.f);
  transpose_cvt<<<dim3(16,16,6), B256, 0, stream>>>(sa_Wo, WtSo, DD, DD, ZD, ZD, 1.f);
  transpose_cvt<<<dim3(16,16,6), B256, 0, stream>>>(ca_Wq, WtCq, DD, DD, ZD, ZD, QSC);
  transpose_cvt<<<dim3(16,16,6), B256, 0, stream>>>(ca_Wk, WtCk, DD, DD, ZD, ZD, 1.f);
  transpose_cvt<<<dim3(16,16,6), B256, 0, stream>>>(ca_Wv, WtCv, DD, DD, ZD, ZD, 1.f);
  transpose_cvt<<<dim3(16,16,6), B256, 0, stream>>>(ca_Wo, WtCo, DD, DD, ZD, ZD, 1.f);
  transpose_cvt<<<dim3(32,16,6), B256, 0, stream>>>(ff_W1, WtF1, DD, FFND, (size_t)DD*FFND, (size_t)DD*FFND, 1.f);
  transpose_cvt<<<dim3(16,32,6), B256, 0, stream>>>(ff_W2, WtF2, FFND, DD, (size_t)DD*FFND, (size_t)DD*FFND, 1.f);
  transpose_cvt<<<dim3(8,8,1),  B256, 0, stream>>>(qs_W1, WtQB,      DM, DM, ZM, ZM, 1.f);
  transpose_cvt<<<dim3(8,8,1),  B256, 0, stream>>>(bb_W1, WtQB + ZM, DM, DM, ZM, ZM, 1.f);
  transpose_cvt<<<dim3(8,8,1),  B256, 0, stream>>>(qs_W2, WtQ2, DM, DM, ZM, ZM, 1.f);
  concat_bias<<<dim3(2), B256, 0, stream>>>(qs_b1, bb_b1, QBB);

  // ---------- pre-loop ----------
  init_x<<<dim3((nTotal+255)/256), B256, 0, stream>>>(tgt, query_pos, X, Xb, QIN, nTotal);
  cvt_mem<<<dim3(NMROWS*DD/8/256), B256, 0, stream>>>(memory, pos, MEMb, MEMVb);
  gemm_f32<<<dim3(DM/64, NQROWS/64), B256, 0, stream>>>(query_pos, nullptr, rp_W1, rp_b1, T256, NQROWS, DM, DM, DM, 1);
  gemm_skinny<<<dim3(NQROWS/4), B256, 0, stream>>>(T256, rp_W2, rp_b2, REFB, NQROWS, 2, DM, DM);
  sine_embed_kernel<<<dim3((NQROWS*DM+255)/256), B256, 0, stream>>>(REFB, SINE);

  const int nredu = (128*QLEN + 3) / 4;
  const int qtiles = (QLEN + 63) / 64;
  for (int l = 0; l < 6; ++l) {
    const size_t wo = (size_t)l*DD*DD, fo = (size_t)l*DD*FFND;
    const float* fb1 = ff_b1 + (size_t)l*FFND;
    const float* fb2 = ff_b2 + (size_t)l*DD;

    // fused qs1 (bf16 out) + bbox1 (f32 out), both ReLU, input Xb[:,256:]
    gemm_mfma_split<<<dim3(8, NQROWS/64), B256, 0, stream>>>(Xb+DM, WtQB, QBB, T256b, T256, NQROWS, 512, DM, DD);
    gemm2<32,0,false><<<dim3(DM/128, NQROWS/32), B256, 0, stream>>>(T256b, WtQ2, qs_b2, PT, NQROWS, DM, DM, DM, 0);
    gemm_skinny_boxes<<<dim3(NQROWS/4), B256, 0, stream>>>(T256, bb_W2, bb_b2, REFB, BOX, CS, NQROWS, DM, DM);
    bias_kernel<<<dim3((BATCH*QLEN*QLEN+255)/256), B256, 0, stream>>>(BOX, CS, BIAS);

    // ---- self-attention (QIN written by init_x / previous ln3); NS=1 direct out ----
    gemm2<64,2,false><<<dim3(1024/128, NQROWS/64), B256, 0, stream>>>(QIN, WtSqk + (size_t)l*2*ZD, nullptr, QKb, NQROWS, 1024, DD, DD, QLEN);
    gemm2_vt<64><<<dim3(DD/128, BATCH*5), B256, 0, stream>>>(Xb, WtSv+wo, VTsa, QLEN, DD, DD, SAKPAD, 5);
    attn2<true,true,1><<<dim3(128, qtiles, 1), B256, 0, stream>>>(QKb, QKb, VTsa, BIAS, AOb, OPARTU, ML, QLEN, QLEN, SAKPAD, 16, 16, 8);
    gemm2<32,0,false><<<dim3(DD/128, NQROWS/32), B256, 0, stream>>>(AOb, WtSo+wo, nullptr, RES, NQROWS, DD, DD, DD, 0);
    ln_residual_t<2><<<dim3(NQROWS), B256, 0, stream>>>(X, RES, Xb, query_pos, SINE, PT, QIN);

    // ---- cross-attention (QIN written by ln1 above) ----
    gemm2<32,2,false><<<dim3(DD/128, NQROWS/32), B256, 0, stream>>>(QIN, WtCq+wo, nullptr, PQb, NQROWS, DD, DD, DD, QLEN);
    gemm2<128,2,false><<<dim3(DD/128, NMROWS/128), B256, 0, stream>>>(MEMb,  WtCk+wo, nullptr, PKb, NMROWS, DD, DD, DD, SLEN);
    gemm2_vt<128><<<dim3(DD/128, BATCH*8), B256, 0, stream>>>(MEMVb, WtCv+wo, PVb, SLEN, DD, DD, SLEN, 8);
    attn2<false,false,2><<<dim3(128, qtiles, 2), B256, 0, stream>>>(PQb, PKb, PVb, nullptr, nullptr, OPARTU, ML, QLEN, SLEN, SLEN, 8, 8, 0);
    attn_reduce<2><<<dim3(nredu), B256, 0, stream>>>(OPARTU, ML, AOb, QLEN);
    gemm2<32,0,false><<<dim3(DD/128, NQROWS/32), B256, 0, stream>>>(AOb, WtCo+wo, nullptr, RES, NQROWS, DD, DD, DD, 0);
    ln_residual_t<0><<<dim3(NQROWS), B256, 0, stream>>>(X, RES, Xb, nullptr, nullptr, nullptr, nullptr);

    // ---- FFN ----
    gemm2<64,1,true ><<<dim3(FFND/128, NQROWS/64), B256, 0, stream>>>(Xb, WtF1+fo, fb1, HIDb, NQROWS, FFND, DD, DD, 0);
    gemm2<32,0,false><<<dim3(DD/128, NQROWS/32), B256, 0, stream>>>(HIDb, WtF2+fo, fb2, RES, NQROWS, DD, FFND, FFND, 0);
    ln_residual_t<1><<<dim3(NQROWS), B256, 0, stream>>>(X, RES, Xb, query_pos, nullptr, nullptr, QIN);
  }

  copy_f32<<<dim3((nTotal+255)/256), B256, 0, stream>>>(X, (float*)d_out, out_size);
}